// Round 8
// baseline (385.106 us; speedup 1.0000x reference)
//
#include <hip/hip_runtime.h>
#include <hip/hip_bf16.h>
#include <stdint.h>

#define MAXDEG 64

static __device__ __forceinline__ float us2f(unsigned short u) {
    union { float f; unsigned int i; } cv; cv.i = ((unsigned int)u) << 16; return cv.f;
}
static __device__ __forceinline__ unsigned short f2us(float f) {
    __hip_bfloat16 h = __float2bfloat16(f);   // RNE
    return *(unsigned short*)&h;
}

// ---------------- setup: degree + ELL adjacency (incoming edges per dst) ----------------
__global__ void k_build_ell(const int* __restrict__ ei, const float* __restrict__ ew,
                            float* __restrict__ deg, unsigned* __restrict__ cnt,
                            int2* __restrict__ ell, int E)
{
    int e = blockIdx.x * 256 + threadIdx.x;
    if (e >= E) return;
    int s = ei[e], d = ei[E + e];
    float w = ew[e];
    atomicAdd(&deg[d], w);
    unsigned slot = atomicAdd(&cnt[d], 1u);
    if (slot < MAXDEG) ell[(size_t)d * MAXDEG + slot] = make_int2(s, __float_as_int(w));
}

__global__ void k_dis(const float* __restrict__ deg, float* __restrict__ dis, int N)
{
    int i = blockIdx.x * 256 + threadIdx.x;
    if (i < N) dis[i] = rsqrtf(deg[i] + 1.0f);
}

// ---------------- layer A: conv1d(K=3,pad1) + InstanceNorm(T) + ReLU + (h @ gw) --------
// One wave per node (lane = out channel), 8 nodes per block (512 thr) so the
// block-shared bf16 weight tile amortizes over 2x waves.
// LDS: CIN=64: 24832 (w) + 28672 (tile) = 53504 -> 3 blocks/CU = 24 waves/CU.
//      CIN=32: 12544 + 24576 = 37120 -> 4 blocks/CU = 32 waves/CU.
// Output xw: bf16 [N][T*64] (halves layer-B gather traffic); accumulation f32.
template<int CIN, bool FIRST>
__global__ __launch_bounds__(512, 6) void k_layer_a(
    const float* __restrict__ x_in,
    const float* __restrict__ cw,     // [64][CIN][3] f32
    const float* __restrict__ cb, const float* __restrict__ gm, const float* __restrict__ bt,
    const float* __restrict__ gw,     // [64][64] f32 (global, L2-broadcast)
    unsigned short* __restrict__ xw_out, int N)
{
    constexpr int WROWS = CIN * 3;
    constexpr int WSTR  = WROWS + 2;             // even; stride%32==1 in banks -> conflict-free
    constexpr int TILE  = (14 * CIN > 768) ? 14 * CIN : 768;
    __shared__ unsigned short lwh[64 * WSTR];    // [c][ci*3+k] bf16
    __shared__ __align__(16) float tile[8][TILE];

    const int tid = threadIdx.x;
    const int nn = tid >> 6;
    const int c = tid & 63;
    int n = blockIdx.x * 8 + nn;
    if (n >= N) n = N - 1;

    // cooperative weight staging f32 -> bf16 (block-shared)
    for (int g = tid; g < 64 * WROWS; g += 512) {
        int row = g / WROWS, col = g - row * WROWS;
        lwh[row * WSTR + col] = f2us(cw[g]);
    }

    // stage x into tile rows t=-1..12 (rows 0..13), row stride CIN (wave-private slice)
    if (FIRST) {
        #pragma unroll
        for (int it = 0; it < (12 * CIN) / 64; ++it) {
            int i = it * 64 + c;
            int t = i / CIN, ci = i - t * CIN;
            tile[nn][(t + 1) * CIN + ci] = x_in[((size_t)t * N + n) * CIN + ci];
        }
    } else {
        const float* src = x_in + (size_t)n * 768;
        #pragma unroll
        for (int j = 0; j < 3; ++j)
            *(float4*)&tile[nn][CIN + j * 256 + c * 4] = *(const float4*)(src + j * 256 + c * 4);
    }
    if (c < CIN) { tile[nn][c] = 0.f; tile[nn][13 * CIN + c] = 0.f; }
    __syncthreads();   // weights staged by all threads

    // conv: acc[t] = bias + sum_ci sum_k x[t+k-1][ci] * w[c][ci][k]
    float acc[12];
    {
        const float bias = cb[c];
        #pragma unroll
        for (int t = 0; t < 12; ++t) acc[t] = bias;
        const float* xt = tile[nn];
        const unsigned short* wrow = lwh + c * WSTR;
        #pragma unroll
        for (int cq = 0; cq < CIN / 4; ++cq) {
            float wv[12];
            #pragma unroll
            for (int rp = 0; rp < 6; ++rp) {
                ushort2 pw = *(const ushort2*)(wrow + cq * 12 + rp * 2);
                wv[rp * 2 + 0] = us2f(pw.x);
                wv[rp * 2 + 1] = us2f(pw.y);
            }
            float4 r0 = *(const float4*)(xt + cq * 4);
            float4 r1 = *(const float4*)(xt + CIN + cq * 4);
            #pragma unroll
            for (int t = 0; t < 12; ++t) {
                float4 r2 = *(const float4*)(xt + (t + 2) * CIN + cq * 4);
                acc[t] = fmaf(r0.x, wv[0], acc[t]);
                acc[t] = fmaf(r1.x, wv[1], acc[t]);
                acc[t] = fmaf(r2.x, wv[2], acc[t]);
                acc[t] = fmaf(r0.y, wv[3], acc[t]);
                acc[t] = fmaf(r1.y, wv[4], acc[t]);
                acc[t] = fmaf(r2.y, wv[5], acc[t]);
                acc[t] = fmaf(r0.z, wv[6], acc[t]);
                acc[t] = fmaf(r1.z, wv[7], acc[t]);
                acc[t] = fmaf(r2.z, wv[8], acc[t]);
                acc[t] = fmaf(r0.w, wv[9], acc[t]);
                acc[t] = fmaf(r1.w, wv[10], acc[t]);
                acc[t] = fmaf(r2.w, wv[11], acc[t]);
                r0 = r1; r1 = r2;
            }
        }
    }
    // InstanceNorm over T (biased var) + affine + ReLU  (register-only per (n,c))
    float mu = 0.f;
    #pragma unroll
    for (int t = 0; t < 12; ++t) mu += acc[t];
    mu *= (1.f / 12.f);
    float var = 0.f;
    #pragma unroll
    for (int t = 0; t < 12; ++t) { float d = acc[t] - mu; var = fmaf(d, d, var); }
    var *= (1.f / 12.f);
    const float sc = rsqrtf(var + 1e-5f) * gm[c];
    const float sb = bt[c];
    // reuse wave-private tile slice as h[t][64] (no cross-wave access -> no barrier)
    #pragma unroll
    for (int t = 0; t < 12; ++t) {
        float h = fmaf(acc[t] - mu, sc, sb);
        tile[nn][t * 64 + c] = h > 0.f ? h : 0.f;
    }

    // xw[t][d] = sum_cc h[t][cc] * gw[cc][d]; d = lane; gw rows from global (coalesced, f32)
    float xw[12];
    #pragma unroll
    for (int t = 0; t < 12; ++t) xw[t] = 0.f;
    #pragma unroll
    for (int cq = 0; cq < 16; ++cq) {
        float g0 = gw[(cq * 4 + 0) * 64 + c];
        float g1 = gw[(cq * 4 + 1) * 64 + c];
        float g2 = gw[(cq * 4 + 2) * 64 + c];
        float g3 = gw[(cq * 4 + 3) * 64 + c];
        #pragma unroll
        for (int t = 0; t < 12; ++t) {
            float4 hv = *(const float4*)&tile[nn][t * 64 + cq * 4];
            xw[t] = fmaf(hv.x, g0, xw[t]);
            xw[t] = fmaf(hv.y, g1, xw[t]);
            xw[t] = fmaf(hv.z, g2, xw[t]);
            xw[t] = fmaf(hv.w, g3, xw[t]);
        }
    }
    unsigned short* dst = xw_out + (size_t)n * 768 + c;
    #pragma unroll
    for (int t = 0; t < 12; ++t) dst[t * 64] = f2us(xw[t]);
}

// ---------------- layer B: ELL aggregation (+ fused mean_t + 64x32 head if FINAL) ------
// One wave per dst node; lane L owns row elements {j*256 + 4L + m}, j=0..2, m=0..3
// (flat index i = t*64+c). xw rows are bf16: 3 ushort4 (8B) coalesced loads per lane.
#define ACCE(NRM, V0, V1, V2)                                                          \
    a[0] = fmaf(NRM, us2f(V0.x), a[0]);  a[1] = fmaf(NRM, us2f(V0.y), a[1]);           \
    a[2] = fmaf(NRM, us2f(V0.z), a[2]);  a[3] = fmaf(NRM, us2f(V0.w), a[3]);           \
    a[4] = fmaf(NRM, us2f(V1.x), a[4]);  a[5] = fmaf(NRM, us2f(V1.y), a[5]);           \
    a[6] = fmaf(NRM, us2f(V1.z), a[6]);  a[7] = fmaf(NRM, us2f(V1.w), a[7]);           \
    a[8] = fmaf(NRM, us2f(V2.x), a[8]);  a[9] = fmaf(NRM, us2f(V2.y), a[9]);           \
    a[10] = fmaf(NRM, us2f(V2.z), a[10]); a[11] = fmaf(NRM, us2f(V2.w), a[11]);

template<bool FINAL>
__global__ __launch_bounds__(256) void k_layer_b(
    const unsigned short* __restrict__ xw, const int2* __restrict__ ell,
    const unsigned* __restrict__ cnt, const float* __restrict__ dis,
    const float* __restrict__ gb, float* __restrict__ aggout,
    const float* __restrict__ ow, const float* __restrict__ ob,
    float* __restrict__ dout, int N)
{
    __shared__ __align__(16) float hbuf[4][64];
    const int tid = threadIdx.x;
    const int nn = tid >> 6, L = tid & 63;
    int n = blockIdx.x * 4 + nn;
    if (n >= N) n = N - 1;
    const float dn = dis[n];
    const float d2 = dn * dn;

    float a[12];
    {   // self loop: d2 * xw[n] + gb
        const unsigned short* self = xw + (size_t)n * 768 + L * 4;
        ushort4 v0 = *(const ushort4*)self;
        ushort4 v1 = *(const ushort4*)(self + 256);
        ushort4 v2 = *(const ushort4*)(self + 512);
        const int c0 = (L * 4) & 63;
        const float g0 = gb[c0], g1 = gb[c0 + 1], g2 = gb[c0 + 2], g3 = gb[c0 + 3];
        a[0] = fmaf(d2, us2f(v0.x), g0); a[1] = fmaf(d2, us2f(v0.y), g1);
        a[2] = fmaf(d2, us2f(v0.z), g2); a[3] = fmaf(d2, us2f(v0.w), g3);
        a[4] = fmaf(d2, us2f(v1.x), g0); a[5] = fmaf(d2, us2f(v1.y), g1);
        a[6] = fmaf(d2, us2f(v1.z), g2); a[7] = fmaf(d2, us2f(v1.w), g3);
        a[8] = fmaf(d2, us2f(v2.x), g0); a[9] = fmaf(d2, us2f(v2.y), g1);
        a[10] = fmaf(d2, us2f(v2.z), g2); a[11] = fmaf(d2, us2f(v2.w), g3);
    }

    unsigned dg = cnt[n];
    if (dg > MAXDEG) dg = MAXDEG;
    const int2* row = ell + (size_t)n * MAXDEG;
    unsigned e = 0;
    for (; e + 2 <= dg; e += 2) {
        int2 pa = row[e], pb = row[e + 1];
        unsigned sa = (unsigned)pa.x, sb = (unsigned)pb.x;
        if (sa >= (unsigned)N || sb >= (unsigned)N) break;   // defensive
        float na = dis[sa] * __int_as_float(pa.y) * dn;
        float nb = dis[sb] * __int_as_float(pb.y) * dn;
        const unsigned short* qa = xw + (size_t)sa * 768 + L * 4;
        const unsigned short* qb = xw + (size_t)sb * 768 + L * 4;
        ushort4 va0 = *(const ushort4*)qa;
        ushort4 va1 = *(const ushort4*)(qa + 256);
        ushort4 va2 = *(const ushort4*)(qa + 512);
        ushort4 vb0 = *(const ushort4*)qb;
        ushort4 vb1 = *(const ushort4*)(qb + 256);
        ushort4 vb2 = *(const ushort4*)(qb + 512);
        ACCE(na, va0, va1, va2)
        ACCE(nb, vb0, vb1, vb2)
    }
    for (; e < dg; ++e) {
        int2 pa = row[e];
        unsigned sa = (unsigned)pa.x;
        if (sa >= (unsigned)N) continue;
        float na = dis[sa] * __int_as_float(pa.y) * dn;
        const unsigned short* qa = xw + (size_t)sa * 768 + L * 4;
        ushort4 va0 = *(const ushort4*)qa;
        ushort4 va1 = *(const ushort4*)(qa + 256);
        ushort4 va2 = *(const ushort4*)(qa + 512);
        ACCE(na, va0, va1, va2)
    }

    if (!FINAL) {
        float* o = aggout + (size_t)n * 768 + L * 4;
        *(float4*)o = make_float4(a[0], a[1], a[2], a[3]);
        *(float4*)(o + 256) = make_float4(a[4], a[5], a[6], a[7]);
        *(float4*)(o + 512) = make_float4(a[8], a[9], a[10], a[11]);
    } else {
        // mean over T: lane L=16q+b, comp m holds channel 4b+m at t in {q,4+q,8+q};
        // xor over L bits 4,5 sums q=0..3 -> all 12 t's.
        float s0 = a[0] + a[4] + a[8];
        float s1 = a[1] + a[5] + a[9];
        float s2 = a[2] + a[6] + a[10];
        float s3 = a[3] + a[7] + a[11];
        s0 += __shfl_xor(s0, 16); s1 += __shfl_xor(s1, 16);
        s2 += __shfl_xor(s2, 16); s3 += __shfl_xor(s3, 16);
        s0 += __shfl_xor(s0, 32); s1 += __shfl_xor(s1, 32);
        s2 += __shfl_xor(s2, 32); s3 += __shfl_xor(s3, 32);
        if (L < 16) {
            const float inv12 = 1.f / 12.f;
            hbuf[nn][L * 4 + 0] = s0 * inv12;
            hbuf[nn][L * 4 + 1] = s1 * inv12;
            hbuf[nn][L * 4 + 2] = s2 * inv12;
            hbuf[nn][L * 4 + 3] = s3 * inv12;
        }
        __syncthreads();
        if (L < 32) {
            float oa = ob[L];
            #pragma unroll
            for (int cc = 0; cc < 64; ++cc)
                oa = fmaf(hbuf[nn][cc], ow[cc * 32 + L], oa);
            dout[(size_t)n * 32 + L] = oa;
        }
    }
}

extern "C" void kernel_launch(void* const* d_in, const int* in_sizes, int n_in,
                              void* d_out, int out_size, void* d_ws, size_t ws_size,
                              hipStream_t stream)
{
    const float* x   = (const float*)d_in[0];
    const int*   ei  = (const int*)d_in[1];
    const float* ew  = (const float*)d_in[2];
    const float* cw1 = (const float*)d_in[3];
    const float* cb1 = (const float*)d_in[4];
    const float* gm1 = (const float*)d_in[5];
    const float* bt1 = (const float*)d_in[6];
    const float* gw1 = (const float*)d_in[7];
    const float* gb1 = (const float*)d_in[8];
    const float* cw2 = (const float*)d_in[9];
    const float* cb2 = (const float*)d_in[10];
    const float* gm2 = (const float*)d_in[11];
    const float* bt2 = (const float*)d_in[12];
    const float* gw2 = (const float*)d_in[13];
    const float* gb2 = (const float*)d_in[14];
    const float* ow  = (const float*)d_in[15];
    const float* ob  = (const float*)d_in[16];

    const int N = in_sizes[0] / (12 * 32);
    const int E = in_sizes[2];

    // workspace layout
    char* p0 = (char*)d_ws;
    char* p = p0;
    float* deg = (float*)p;          p += (size_t)N * 4;
    unsigned* cnt = (unsigned*)p;    p += (size_t)N * 4;   // adjacent to deg: one memset
    float* dis = (float*)p;          p += (size_t)N * 4;
    p = (char*)(((uintptr_t)p + 255) & ~(uintptr_t)255);
    int2* ell = (int2*)p;            p += (size_t)N * MAXDEG * 8;
    p = (char*)(((uintptr_t)p + 255) & ~(uintptr_t)255);
    unsigned short* bufXW = (unsigned short*)p; p += (size_t)N * 768 * 2;  // xw, bf16
    float* bufAgg = (float*)p;                  p += (size_t)N * 768 * 4;  // agg, f32

    const size_t need = (size_t)(p - p0);
    if (ws_size < need) {
        hipMemsetAsync(d_out, 0, (size_t)out_size * 4, stream);   // sentinel
        return;
    }

    hipMemsetAsync(deg, 0, (size_t)N * 8, stream);

    const int eb  = (E + 255) / 256;
    const int nb8 = (N + 7) / 8;
    const int nb4 = (N + 3) / 4;
    k_build_ell<<<eb, 256, 0, stream>>>(ei, ew, deg, cnt, ell, E);
    k_dis<<<(N + 255) / 256, 256, 0, stream>>>(deg, dis, N);

    // layer 1: conv+IN+ReLU+GEMM fused -> bufXW (bf16); agg -> bufAgg (f32)
    k_layer_a<32, true ><<<nb8, 512, 0, stream>>>(x, cw1, cb1, gm1, bt1, gw1, bufXW, N);
    k_layer_b<false><<<nb4, 256, 0, stream>>>(bufXW, ell, cnt, dis, gb1, bufAgg, nullptr, nullptr, nullptr, N);
    // layer 2 + fused mean/head
    k_layer_a<64, false><<<nb8, 512, 0, stream>>>(bufAgg, cw2, cb2, gm2, bt2, gw2, bufXW, N);
    k_layer_b<true ><<<nb4, 256, 0, stream>>>(bufXW, ell, cnt, dis, gb2, nullptr, ow, ob, (float*)d_out, N);
}

// Round 9
// 317.223 us; speedup vs baseline: 1.2140x; 1.2140x over previous
//
#include <hip/hip_runtime.h>
#include <hip/hip_bf16.h>
#include <stdint.h>

#define MAXDEG 64

static __device__ __forceinline__ float us2f(unsigned short u) {
    union { float f; unsigned int i; } cv; cv.i = ((unsigned int)u) << 16; return cv.f;
}
static __device__ __forceinline__ unsigned short f2us(float f) {
    __hip_bfloat16 h = __float2bfloat16(f);   // RNE
    return *(unsigned short*)&h;
}

// ---------------- setup: degree + ELL adjacency (incoming edges per dst) ----------------
__global__ void k_build_ell(const int* __restrict__ ei, const float* __restrict__ ew,
                            float* __restrict__ deg, unsigned* __restrict__ cnt,
                            int2* __restrict__ ell, int E)
{
    int e = blockIdx.x * 256 + threadIdx.x;
    if (e >= E) return;
    int s = ei[e], d = ei[E + e];
    float w = ew[e];
    atomicAdd(&deg[d], w);
    unsigned slot = atomicAdd(&cnt[d], 1u);
    if (slot < MAXDEG) ell[(size_t)d * MAXDEG + slot] = make_int2(s, __float_as_int(w));
}

__global__ void k_dis(const float* __restrict__ deg, float* __restrict__ dis, int N)
{
    int i = blockIdx.x * 256 + threadIdx.x;
    if (i < N) dis[i] = rsqrtf(deg[i] + 1.0f);
}

// ---------------- layer A: conv1d(K=3,pad1) + InstanceNorm(T) + ReLU + (h @ gw) --------
// One wave per node (lane = out channel), 8 nodes per block (512 thr); block-shared
// bf16 conv-weight tile amortizes over 8 waves.
// LDS: CIN=64: 24832 (w) + 28672 (tile) = 53504 -> 3 blocks/CU (24 waves, 75%).
//      CIN=32: 12544 + 24576 = 37120 -> 4 blocks/CU (32 waves, 100%).
// launch_bounds min-waves=4 (VGPR cap 128): round-8's min=6 forced VGPR=40 -> spills
// (FETCH+WRITE 420MB/dispatch scratch traffic). Natural allocation is ~64 VGPR.
template<int CIN, bool FIRST>
__global__ __launch_bounds__(512, 4) void k_layer_a(
    const float* __restrict__ x_in,
    const float* __restrict__ cw,     // [64][CIN][3] f32
    const float* __restrict__ cb, const float* __restrict__ gm, const float* __restrict__ bt,
    const float* __restrict__ gw,     // [64][64] f32 (global, L2-broadcast)
    unsigned short* __restrict__ xw_out, int N)
{
    constexpr int WROWS = CIN * 3;
    constexpr int WSTR  = WROWS + 2;             // word-stride %32==1 -> conflict-free rows
    constexpr int TILE  = (14 * CIN > 768) ? 14 * CIN : 768;
    __shared__ unsigned short lwh[64 * WSTR];    // [c][ci*3+k] bf16
    __shared__ __align__(16) float tile[8][TILE];

    const int tid = threadIdx.x;
    const int nn = tid >> 6;
    const int c = tid & 63;
    int n = blockIdx.x * 8 + nn;
    if (n >= N) n = N - 1;

    // cooperative weight staging f32 -> bf16 (block-shared)
    for (int g = tid; g < 64 * WROWS; g += 512) {
        int row = g / WROWS, col = g - row * WROWS;
        lwh[row * WSTR + col] = f2us(cw[g]);
    }

    // stage x into tile rows t=-1..12 (rows 0..13), row stride CIN (wave-private slice)
    if (FIRST) {
        #pragma unroll
        for (int it = 0; it < (12 * CIN) / 64; ++it) {
            int i = it * 64 + c;
            int t = i / CIN, ci = i - t * CIN;
            tile[nn][(t + 1) * CIN + ci] = x_in[((size_t)t * N + n) * CIN + ci];
        }
    } else {
        const float* src = x_in + (size_t)n * 768;
        #pragma unroll
        for (int j = 0; j < 3; ++j)
            *(float4*)&tile[nn][CIN + j * 256 + c * 4] = *(const float4*)(src + j * 256 + c * 4);
    }
    if (c < CIN) { tile[nn][c] = 0.f; tile[nn][13 * CIN + c] = 0.f; }
    __syncthreads();   // weights staged by all threads

    // conv: acc[t] = bias + sum_ci sum_k x[t+k-1][ci] * w[c][ci][k]
    float acc[12];
    {
        const float bias = cb[c];
        #pragma unroll
        for (int t = 0; t < 12; ++t) acc[t] = bias;
        const float* xt = tile[nn];
        const unsigned short* wrow = lwh + c * WSTR;
        #pragma unroll
        for (int cq = 0; cq < CIN / 4; ++cq) {
            float wv[12];
            #pragma unroll
            for (int rp = 0; rp < 6; ++rp) {
                ushort2 pw = *(const ushort2*)(wrow + cq * 12 + rp * 2);
                wv[rp * 2 + 0] = us2f(pw.x);
                wv[rp * 2 + 1] = us2f(pw.y);
            }
            float4 r0 = *(const float4*)(xt + cq * 4);
            float4 r1 = *(const float4*)(xt + CIN + cq * 4);
            #pragma unroll
            for (int t = 0; t < 12; ++t) {
                float4 r2 = *(const float4*)(xt + (t + 2) * CIN + cq * 4);
                acc[t] = fmaf(r0.x, wv[0], acc[t]);
                acc[t] = fmaf(r1.x, wv[1], acc[t]);
                acc[t] = fmaf(r2.x, wv[2], acc[t]);
                acc[t] = fmaf(r0.y, wv[3], acc[t]);
                acc[t] = fmaf(r1.y, wv[4], acc[t]);
                acc[t] = fmaf(r2.y, wv[5], acc[t]);
                acc[t] = fmaf(r0.z, wv[6], acc[t]);
                acc[t] = fmaf(r1.z, wv[7], acc[t]);
                acc[t] = fmaf(r2.z, wv[8], acc[t]);
                acc[t] = fmaf(r0.w, wv[9], acc[t]);
                acc[t] = fmaf(r1.w, wv[10], acc[t]);
                acc[t] = fmaf(r2.w, wv[11], acc[t]);
                r0 = r1; r1 = r2;
            }
        }
    }
    // InstanceNorm over T (biased var) + affine + ReLU  (register-only per (n,c))
    float mu = 0.f;
    #pragma unroll
    for (int t = 0; t < 12; ++t) mu += acc[t];
    mu *= (1.f / 12.f);
    float var = 0.f;
    #pragma unroll
    for (int t = 0; t < 12; ++t) { float d = acc[t] - mu; var = fmaf(d, d, var); }
    var *= (1.f / 12.f);
    const float sc = rsqrtf(var + 1e-5f) * gm[c];
    const float sb = bt[c];
    // reuse wave-private tile slice as h[t][64] (no cross-wave access -> no barrier)
    #pragma unroll
    for (int t = 0; t < 12; ++t) {
        float h = fmaf(acc[t] - mu, sc, sb);
        tile[nn][t * 64 + c] = h > 0.f ? h : 0.f;
    }

    // xw[t][d] = sum_cc h[t][cc] * gw[cc][d]; d = lane; gw rows from global (coalesced, f32)
    float xw[12];
    #pragma unroll
    for (int t = 0; t < 12; ++t) xw[t] = 0.f;
    #pragma unroll
    for (int cq = 0; cq < 16; ++cq) {
        float g0 = gw[(cq * 4 + 0) * 64 + c];
        float g1 = gw[(cq * 4 + 1) * 64 + c];
        float g2 = gw[(cq * 4 + 2) * 64 + c];
        float g3 = gw[(cq * 4 + 3) * 64 + c];
        #pragma unroll
        for (int t = 0; t < 12; ++t) {
            float4 hv = *(const float4*)&tile[nn][t * 64 + cq * 4];
            xw[t] = fmaf(hv.x, g0, xw[t]);
            xw[t] = fmaf(hv.y, g1, xw[t]);
            xw[t] = fmaf(hv.z, g2, xw[t]);
            xw[t] = fmaf(hv.w, g3, xw[t]);
        }
    }
    unsigned short* dst = xw_out + (size_t)n * 768 + c;
    #pragma unroll
    for (int t = 0; t < 12; ++t) dst[t * 64] = f2us(xw[t]);
}

// ---------------- layer B: ELL aggregation (+ fused mean_t + 64x32 head if FINAL) ------
// One wave per dst node; lane L owns row elements {j*256 + 4L + m}, j=0..2, m=0..3
// (flat index i = t*64+c). xw rows are bf16: 3 ushort4 (8B) coalesced loads per lane.
#define ACCE(NRM, V0, V1, V2)                                                          \
    a[0] = fmaf(NRM, us2f(V0.x), a[0]);  a[1] = fmaf(NRM, us2f(V0.y), a[1]);           \
    a[2] = fmaf(NRM, us2f(V0.z), a[2]);  a[3] = fmaf(NRM, us2f(V0.w), a[3]);           \
    a[4] = fmaf(NRM, us2f(V1.x), a[4]);  a[5] = fmaf(NRM, us2f(V1.y), a[5]);           \
    a[6] = fmaf(NRM, us2f(V1.z), a[6]);  a[7] = fmaf(NRM, us2f(V1.w), a[7]);           \
    a[8] = fmaf(NRM, us2f(V2.x), a[8]);  a[9] = fmaf(NRM, us2f(V2.y), a[9]);           \
    a[10] = fmaf(NRM, us2f(V2.z), a[10]); a[11] = fmaf(NRM, us2f(V2.w), a[11]);

template<bool FINAL>
__global__ __launch_bounds__(256) void k_layer_b(
    const unsigned short* __restrict__ xw, const int2* __restrict__ ell,
    const unsigned* __restrict__ cnt, const float* __restrict__ dis,
    const float* __restrict__ gb, float* __restrict__ aggout,
    const float* __restrict__ ow, const float* __restrict__ ob,
    float* __restrict__ dout, int N)
{
    __shared__ __align__(16) float hbuf[4][64];
    const int tid = threadIdx.x;
    const int nn = tid >> 6, L = tid & 63;
    int n = blockIdx.x * 4 + nn;
    if (n >= N) n = N - 1;
    const float dn = dis[n];
    const float d2 = dn * dn;

    float a[12];
    {   // self loop: d2 * xw[n] + gb
        const unsigned short* self = xw + (size_t)n * 768 + L * 4;
        ushort4 v0 = *(const ushort4*)self;
        ushort4 v1 = *(const ushort4*)(self + 256);
        ushort4 v2 = *(const ushort4*)(self + 512);
        const int c0 = (L * 4) & 63;
        const float g0 = gb[c0], g1 = gb[c0 + 1], g2 = gb[c0 + 2], g3 = gb[c0 + 3];
        a[0] = fmaf(d2, us2f(v0.x), g0); a[1] = fmaf(d2, us2f(v0.y), g1);
        a[2] = fmaf(d2, us2f(v0.z), g2); a[3] = fmaf(d2, us2f(v0.w), g3);
        a[4] = fmaf(d2, us2f(v1.x), g0); a[5] = fmaf(d2, us2f(v1.y), g1);
        a[6] = fmaf(d2, us2f(v1.z), g2); a[7] = fmaf(d2, us2f(v1.w), g3);
        a[8] = fmaf(d2, us2f(v2.x), g0); a[9] = fmaf(d2, us2f(v2.y), g1);
        a[10] = fmaf(d2, us2f(v2.z), g2); a[11] = fmaf(d2, us2f(v2.w), g3);
    }

    unsigned dg = cnt[n];
    if (dg > MAXDEG) dg = MAXDEG;
    const int2* row = ell + (size_t)n * MAXDEG;
    unsigned e = 0;
    for (; e + 2 <= dg; e += 2) {
        int2 pa = row[e], pb = row[e + 1];
        unsigned sa = (unsigned)pa.x, sb = (unsigned)pb.x;
        if (sa >= (unsigned)N || sb >= (unsigned)N) break;   // defensive
        float na = dis[sa] * __int_as_float(pa.y) * dn;
        float nb = dis[sb] * __int_as_float(pb.y) * dn;
        const unsigned short* qa = xw + (size_t)sa * 768 + L * 4;
        const unsigned short* qb = xw + (size_t)sb * 768 + L * 4;
        ushort4 va0 = *(const ushort4*)qa;
        ushort4 va1 = *(const ushort4*)(qa + 256);
        ushort4 va2 = *(const ushort4*)(qa + 512);
        ushort4 vb0 = *(const ushort4*)qb;
        ushort4 vb1 = *(const ushort4*)(qb + 256);
        ushort4 vb2 = *(const ushort4*)(qb + 512);
        ACCE(na, va0, va1, va2)
        ACCE(nb, vb0, vb1, vb2)
    }
    for (; e < dg; ++e) {
        int2 pa = row[e];
        unsigned sa = (unsigned)pa.x;
        if (sa >= (unsigned)N) continue;
        float na = dis[sa] * __int_as_float(pa.y) * dn;
        const unsigned short* qa = xw + (size_t)sa * 768 + L * 4;
        ushort4 va0 = *(const ushort4*)qa;
        ushort4 va1 = *(const ushort4*)(qa + 256);
        ushort4 va2 = *(const ushort4*)(qa + 512);
        ACCE(na, va0, va1, va2)
    }

    if (!FINAL) {
        float* o = aggout + (size_t)n * 768 + L * 4;
        *(float4*)o = make_float4(a[0], a[1], a[2], a[3]);
        *(float4*)(o + 256) = make_float4(a[4], a[5], a[6], a[7]);
        *(float4*)(o + 512) = make_float4(a[8], a[9], a[10], a[11]);
    } else {
        // mean over T: lane L=16q+b, comp m holds channel 4b+m at t in {q,4+q,8+q};
        // xor over L bits 4,5 sums q=0..3 -> all 12 t's.
        float s0 = a[0] + a[4] + a[8];
        float s1 = a[1] + a[5] + a[9];
        float s2 = a[2] + a[6] + a[10];
        float s3 = a[3] + a[7] + a[11];
        s0 += __shfl_xor(s0, 16); s1 += __shfl_xor(s1, 16);
        s2 += __shfl_xor(s2, 16); s3 += __shfl_xor(s3, 16);
        s0 += __shfl_xor(s0, 32); s1 += __shfl_xor(s1, 32);
        s2 += __shfl_xor(s2, 32); s3 += __shfl_xor(s3, 32);
        if (L < 16) {
            const float inv12 = 1.f / 12.f;
            hbuf[nn][L * 4 + 0] = s0 * inv12;
            hbuf[nn][L * 4 + 1] = s1 * inv12;
            hbuf[nn][L * 4 + 2] = s2 * inv12;
            hbuf[nn][L * 4 + 3] = s3 * inv12;
        }
        __syncthreads();
        if (L < 32) {
            float oa = ob[L];
            #pragma unroll
            for (int cc = 0; cc < 64; ++cc)
                oa = fmaf(hbuf[nn][cc], ow[cc * 32 + L], oa);
            dout[(size_t)n * 32 + L] = oa;
        }
    }
}

extern "C" void kernel_launch(void* const* d_in, const int* in_sizes, int n_in,
                              void* d_out, int out_size, void* d_ws, size_t ws_size,
                              hipStream_t stream)
{
    const float* x   = (const float*)d_in[0];
    const int*   ei  = (const int*)d_in[1];
    const float* ew  = (const float*)d_in[2];
    const float* cw1 = (const float*)d_in[3];
    const float* cb1 = (const float*)d_in[4];
    const float* gm1 = (const float*)d_in[5];
    const float* bt1 = (const float*)d_in[6];
    const float* gw1 = (const float*)d_in[7];
    const float* gb1 = (const float*)d_in[8];
    const float* cw2 = (const float*)d_in[9];
    const float* cb2 = (const float*)d_in[10];
    const float* gm2 = (const float*)d_in[11];
    const float* bt2 = (const float*)d_in[12];
    const float* gw2 = (const float*)d_in[13];
    const float* gb2 = (const float*)d_in[14];
    const float* ow  = (const float*)d_in[15];
    const float* ob  = (const float*)d_in[16];

    const int N = in_sizes[0] / (12 * 32);
    const int E = in_sizes[2];

    // workspace layout
    char* p0 = (char*)d_ws;
    char* p = p0;
    float* deg = (float*)p;          p += (size_t)N * 4;
    unsigned* cnt = (unsigned*)p;    p += (size_t)N * 4;   // adjacent to deg: one memset
    float* dis = (float*)p;          p += (size_t)N * 4;
    p = (char*)(((uintptr_t)p + 255) & ~(uintptr_t)255);
    int2* ell = (int2*)p;            p += (size_t)N * MAXDEG * 8;
    p = (char*)(((uintptr_t)p + 255) & ~(uintptr_t)255);
    unsigned short* bufXW = (unsigned short*)p; p += (size_t)N * 768 * 2;  // xw, bf16
    float* bufAgg = (float*)p;                  p += (size_t)N * 768 * 4;  // agg, f32

    const size_t need = (size_t)(p - p0);
    if (ws_size < need) {
        hipMemsetAsync(d_out, 0, (size_t)out_size * 4, stream);   // sentinel
        return;
    }

    hipMemsetAsync(deg, 0, (size_t)N * 8, stream);

    const int eb  = (E + 255) / 256;
    const int nb8 = (N + 7) / 8;
    const int nb4 = (N + 3) / 4;
    k_build_ell<<<eb, 256, 0, stream>>>(ei, ew, deg, cnt, ell, E);
    k_dis<<<(N + 255) / 256, 256, 0, stream>>>(deg, dis, N);

    // layer 1: conv+IN+ReLU+GEMM fused -> bufXW (bf16); agg -> bufAgg (f32)
    k_layer_a<32, true ><<<nb8, 512, 0, stream>>>(x, cw1, cb1, gm1, bt1, gw1, bufXW, N);
    k_layer_b<false><<<nb4, 256, 0, stream>>>(bufXW, ell, cnt, dis, gb1, bufAgg, nullptr, nullptr, nullptr, N);
    // layer 2 + fused mean/head
    k_layer_a<64, false><<<nb8, 512, 0, stream>>>(bufAgg, cw2, cb2, gm2, bt2, gw2, bufXW, N);
    k_layer_b<true ><<<nb4, 256, 0, stream>>>(bufXW, ell, cnt, dis, gb2, nullptr, ow, ob, (float*)d_out, N);
}

// Round 10
// 257.682 us; speedup vs baseline: 1.4945x; 1.2311x over previous
//
#include <hip/hip_runtime.h>
#include <hip/hip_bf16.h>
#include <stdint.h>

#define MAXDEG 64

typedef short s16x8 __attribute__((ext_vector_type(8)));
typedef short s16x4 __attribute__((ext_vector_type(4)));
typedef float f32x4 __attribute__((ext_vector_type(4)));

static __device__ __forceinline__ float us2f(unsigned short u) {
    union { float f; unsigned int i; } cv; cv.i = ((unsigned int)u) << 16; return cv.f;
}
static __device__ __forceinline__ unsigned short f2us(float f) {
    __hip_bfloat16 h = __float2bfloat16(f);   // RNE
    return *(unsigned short*)&h;
}

// ---------------- setup: degree + ELL adjacency (incoming edges per dst) ----------------
__global__ void k_build_ell(const int* __restrict__ ei, const float* __restrict__ ew,
                            float* __restrict__ deg, unsigned* __restrict__ cnt,
                            int2* __restrict__ ell, int E)
{
    int e = blockIdx.x * 256 + threadIdx.x;
    if (e >= E) return;
    int s = ei[e], d = ei[E + e];
    float w = ew[e];
    atomicAdd(&deg[d], w);
    unsigned slot = atomicAdd(&cnt[d], 1u);
    if (slot < MAXDEG) ell[(size_t)d * MAXDEG + slot] = make_int2(s, __float_as_int(w));
}

__global__ void k_dis(const float* __restrict__ deg, float* __restrict__ dis, int N)
{
    int i = blockIdx.x * 256 + threadIdx.x;
    if (i < N) dis[i] = rsqrtf(deg[i] + 1.0f);
}

// ---- precompute edge norm dis[src]*w*dis[dst] into ELL payload (kills the dependent
//      dis[src] load chain in layer_b's inner loop) ----
__global__ void k_norm(int2* __restrict__ ell, const unsigned* __restrict__ cnt,
                       const float* __restrict__ dis, int N)
{
    int idx = blockIdx.x * 256 + threadIdx.x;
    if (idx >= N * MAXDEG) return;
    int n = idx >> 6;               // MAXDEG = 64
    int s = idx & (MAXDEG - 1);
    unsigned dg = cnt[n]; if (dg > MAXDEG) dg = MAXDEG;
    if ((unsigned)s >= dg) return;
    int2 p = ell[idx];
    unsigned sx = (unsigned)p.x;
    float nrm = (sx < (unsigned)N) ? dis[sx] * __int_as_float(p.y) * dis[n] : 0.f;
    ell[idx] = make_int2(p.x, __float_as_int(nrm));
}

// ---------------- layer A (MFMA): conv1d(K=3,pad1) + InstanceNorm(T) + ReLU + (h @ gw) --
// One wave per node, 8 nodes/block (512 thr). Per wave:
//   conv  : D[16 t][64 c] = A_im2col[16][K=3*CIN] @ W[K][64]  (KT x 4 mfma_16x16x32_bf16)
//   IN    : bias cancels under IN (const over T) -> skipped; A rows t=12..15 zeroed so
//           C rows 12..15 are exactly 0 => mu = S/12, var = Sq/12 - mu^2, no masking.
//   h->LDS: C-layout (col=lane&15,row=quad*4+reg) -> stride-72 tile -> A-layout reads.
//   gemm2 : xw[16 t][64 d] = h[16][64] @ gw[64][64]  (2 x 4 mfma)
// LDS: CIN=64: Wt 25600 + gwT 9216 + 8*2304 = 53248 -> 3 blocks/CU (24 waves).
//      CIN=32: 13312 + 9216 + 18432 = 40960 -> 4 blocks/CU.
template<int CIN, bool FIRST>
__global__ __launch_bounds__(512, 4) void k_layer_a(
    const float* __restrict__ x_in,   // FIRST: [T][N][CIN] f32; else agg [N][768] f32
    const float* __restrict__ cw,     // [64][CIN][3] f32
    const float* __restrict__ cb,     // unused: bias cancels under InstanceNorm
    const float* __restrict__ gm, const float* __restrict__ bt,
    const float* __restrict__ gw,     // [64][64] f32
    unsigned short* __restrict__ xw_out, int N)
{
    constexpr int WROWS = CIN * 3;            // im2col K
    constexpr int KT    = WROWS / 32;         // conv K-tiles
    constexpr int WKSTR = WROWS + 8;          // x2B: 400/208 -> 16B-aligned rows, 2-way banks
    __shared__ __align__(16) short Wt[64 * WKSTR];   // Wt[c][k] = cw_flat[c*WROWS+k] (= B[k][c])
    __shared__ __align__(16) short gwT[64 * 72];     // gwT[d][cc] = gw[cc][d]
    __shared__ __align__(16) short xh[8][1152];      // per wave: x tile (14*CIN) then h tile (16*72)
    (void)cb;

    const int tid = threadIdx.x;
    const int nn = tid >> 6;
    const int c = tid & 63;          // lane
    const int m = c & 15;            // MFMA row/col index
    const int q = c >> 4;            // quad
    int n = blockIdx.x * 8 + nn;
    if (n >= N) n = N - 1;

    // ---- stage conv weights (rows = out channel, natural k order) ----
    for (int g = tid; g < 64 * WROWS; g += 512) {
        int row = g / WROWS, col = g - row * WROWS;
        Wt[row * WKSTR + col] = (short)f2us(cw[g]);
    }
    // ---- stage gw transposed ----
    for (int g = tid; g < 4096; g += 512) {
        int cc = g >> 6, d = g & 63;
        gwT[d * 72 + cc] = (short)f2us(gw[g]);
    }
    // ---- stage x tile rows t=-1..12 -> rows 0..13 (bf16), row stride CIN ----
    if (FIRST) {
        #pragma unroll
        for (int it = 0; it < (12 * CIN) / 64; ++it) {
            int i = it * 64 + c;
            int t = i / CIN, ci = i - t * CIN;
            xh[nn][(t + 1) * CIN + ci] = (short)f2us(x_in[((size_t)t * N + n) * CIN + ci]);
        }
    } else {
        const float* src = x_in + (size_t)n * 768;
        #pragma unroll
        for (int j3 = 0; j3 < 3; ++j3) {
            float4 v = *(const float4*)(src + j3 * 256 + c * 4);
            xh[nn][CIN + j3 * 256 + c * 4 + 0] = (short)f2us(v.x);
            xh[nn][CIN + j3 * 256 + c * 4 + 1] = (short)f2us(v.y);
            xh[nn][CIN + j3 * 256 + c * 4 + 2] = (short)f2us(v.z);
            xh[nn][CIN + j3 * 256 + c * 4 + 3] = (short)f2us(v.w);
        }
    }
    if (c < CIN) { xh[nn][c] = 0; xh[nn][13 * CIN + c] = 0; }
    __syncthreads();

    // ---- conv via MFMA: A[t][k] = x_pad[t + k%3][k/3], zero for t>=12 ----
    f32x4 acc[4];
    #pragma unroll
    for (int nt = 0; nt < 4; ++nt) acc[nt] = (f32x4){0.f, 0.f, 0.f, 0.f};
    #pragma unroll
    for (int kt = 0; kt < KT; ++kt) {
        const int kb = kt * 32 + q * 8;
        s16x8 aA;
        #pragma unroll
        for (int j = 0; j < 8; ++j) {
            int k = kb + j;
            int ci = k / 3;
            int kk = k - ci * 3;
            short v = xh[nn][(m + kk) * CIN + ci];   // max idx 1151 -> in-bounds garbage, masked
            aA[j] = (m < 12) ? v : (short)0;
        }
        #pragma unroll
        for (int nt = 0; nt < 4; ++nt) {
            s16x8 bB = *(const s16x8*)&Wt[(nt * 16 + m) * WKSTR + kb];
            acc[nt] = __builtin_amdgcn_mfma_f32_16x16x32_bf16(aA, bB, acc[nt], 0, 0, 0);
        }
    }

    // ---- InstanceNorm over T + ReLU; write h to stride-72 LDS tile (reuses x tile) ----
    #pragma unroll
    for (int nt = 0; nt < 4; ++nt) {
        float s  = acc[nt][0] + acc[nt][1] + acc[nt][2] + acc[nt][3];
        float s2 = acc[nt][0] * acc[nt][0] + acc[nt][1] * acc[nt][1]
                 + acc[nt][2] * acc[nt][2] + acc[nt][3] * acc[nt][3];
        s  += __shfl_xor(s, 16);  s  += __shfl_xor(s, 32);
        s2 += __shfl_xor(s2, 16); s2 += __shfl_xor(s2, 32);
        const float mu  = s * (1.f / 12.f);
        const float var = s2 * (1.f / 12.f) - mu * mu;
        const float scn = rsqrtf(var + 1e-5f) * gm[nt * 16 + m];
        const float sbn = bt[nt * 16 + m];
        #pragma unroll
        for (int reg = 0; reg < 4; ++reg) {
            float h = fmaf(acc[nt][reg] - mu, scn, sbn);
            h = h > 0.f ? h : 0.f;
            xh[nn][(q * 4 + reg) * 72 + nt * 16 + m] = (short)f2us(h);
        }
    }
    // (wave-private tile: same-array ordering is handled by the compiler, no barrier)

    // ---- gemm2 via MFMA: xw = h @ gw ----
    s16x8 a2[2];
    #pragma unroll
    for (int kt2 = 0; kt2 < 2; ++kt2) {
        s16x4 lo = *(const s16x4*)&xh[nn][m * 72 + kt2 * 32 + q * 8];
        s16x4 hi = *(const s16x4*)&xh[nn][m * 72 + kt2 * 32 + q * 8 + 4];
        a2[kt2] = __builtin_shufflevector(lo, hi, 0, 1, 2, 3, 4, 5, 6, 7);
    }
    f32x4 acc2[4];
    #pragma unroll
    for (int nt = 0; nt < 4; ++nt) acc2[nt] = (f32x4){0.f, 0.f, 0.f, 0.f};
    #pragma unroll
    for (int nt = 0; nt < 4; ++nt) {
        #pragma unroll
        for (int kt2 = 0; kt2 < 2; ++kt2) {
            s16x4 blo = *(const s16x4*)&gwT[(nt * 16 + m) * 72 + kt2 * 32 + q * 8];
            s16x4 bhi = *(const s16x4*)&gwT[(nt * 16 + m) * 72 + kt2 * 32 + q * 8 + 4];
            s16x8 b2 = __builtin_shufflevector(blo, bhi, 0, 1, 2, 3, 4, 5, 6, 7);
            acc2[nt] = __builtin_amdgcn_mfma_f32_16x16x32_bf16(a2[kt2], b2, acc2[nt], 0, 0, 0);
        }
    }

    // ---- store xw rows t<12 (C-layout: row=q*4+reg, col=nt*16+m) ----
    unsigned short* dst = xw_out + (size_t)n * 768;
    if (q < 3) {
        #pragma unroll
        for (int nt = 0; nt < 4; ++nt)
            #pragma unroll
            for (int reg = 0; reg < 4; ++reg)
                dst[(q * 4 + reg) * 64 + nt * 16 + m] = f2us(acc2[nt][reg]);
    }
}

// ---------------- layer B: ELL aggregation (+ fused mean_t + 64x32 head if FINAL) ------
// One wave per dst node; lane L owns row elements {j*256 + 4L + m}. Norms precomputed.
#define ACCE(NRM, V0, V1, V2)                                                          \
    a[0] = fmaf(NRM, us2f(V0.x), a[0]);  a[1] = fmaf(NRM, us2f(V0.y), a[1]);           \
    a[2] = fmaf(NRM, us2f(V0.z), a[2]);  a[3] = fmaf(NRM, us2f(V0.w), a[3]);           \
    a[4] = fmaf(NRM, us2f(V1.x), a[4]);  a[5] = fmaf(NRM, us2f(V1.y), a[5]);           \
    a[6] = fmaf(NRM, us2f(V1.z), a[6]);  a[7] = fmaf(NRM, us2f(V1.w), a[7]);           \
    a[8] = fmaf(NRM, us2f(V2.x), a[8]);  a[9] = fmaf(NRM, us2f(V2.y), a[9]);           \
    a[10] = fmaf(NRM, us2f(V2.z), a[10]); a[11] = fmaf(NRM, us2f(V2.w), a[11]);

template<bool FINAL>
__global__ __launch_bounds__(256) void k_layer_b(
    const unsigned short* __restrict__ xw, const int2* __restrict__ ell,
    const unsigned* __restrict__ cnt, const float* __restrict__ dis,
    const float* __restrict__ gb, float* __restrict__ aggout,
    const float* __restrict__ ow, const float* __restrict__ ob,
    float* __restrict__ dout, int N)
{
    __shared__ __align__(16) float hbuf[4][64];
    const int tid = threadIdx.x;
    const int nn = tid >> 6, L = tid & 63;
    int n = blockIdx.x * 4 + nn;
    if (n >= N) n = N - 1;
    const float dn = dis[n];
    const float d2 = dn * dn;

    float a[12];
    {   // self loop: d2 * xw[n] + gb
        const unsigned short* self = xw + (size_t)n * 768 + L * 4;
        ushort4 v0 = *(const ushort4*)self;
        ushort4 v1 = *(const ushort4*)(self + 256);
        ushort4 v2 = *(const ushort4*)(self + 512);
        const int c0 = (L * 4) & 63;
        const float g0 = gb[c0], g1 = gb[c0 + 1], g2 = gb[c0 + 2], g3 = gb[c0 + 3];
        a[0] = fmaf(d2, us2f(v0.x), g0); a[1] = fmaf(d2, us2f(v0.y), g1);
        a[2] = fmaf(d2, us2f(v0.z), g2); a[3] = fmaf(d2, us2f(v0.w), g3);
        a[4] = fmaf(d2, us2f(v1.x), g0); a[5] = fmaf(d2, us2f(v1.y), g1);
        a[6] = fmaf(d2, us2f(v1.z), g2); a[7] = fmaf(d2, us2f(v1.w), g3);
        a[8] = fmaf(d2, us2f(v2.x), g0); a[9] = fmaf(d2, us2f(v2.y), g1);
        a[10] = fmaf(d2, us2f(v2.z), g2); a[11] = fmaf(d2, us2f(v2.w), g3);
    }

    unsigned dg = cnt[n];
    if (dg > MAXDEG) dg = MAXDEG;
    const int2* row = ell + (size_t)n * MAXDEG;
    unsigned e = 0;
    for (; e + 2 <= dg; e += 2) {
        int2 pa = row[e], pb = row[e + 1];
        unsigned sa = (unsigned)pa.x, sb = (unsigned)pb.x;
        if (sa >= (unsigned)N || sb >= (unsigned)N) break;   // defensive
        float na = __int_as_float(pa.y);                     // precomputed norm
        float nb = __int_as_float(pb.y);
        const unsigned short* qa = xw + (size_t)sa * 768 + L * 4;
        const unsigned short* qb = xw + (size_t)sb * 768 + L * 4;
        ushort4 va0 = *(const ushort4*)qa;
        ushort4 va1 = *(const ushort4*)(qa + 256);
        ushort4 va2 = *(const ushort4*)(qa + 512);
        ushort4 vb0 = *(const ushort4*)qb;
        ushort4 vb1 = *(const ushort4*)(qb + 256);
        ushort4 vb2 = *(const ushort4*)(qb + 512);
        ACCE(na, va0, va1, va2)
        ACCE(nb, vb0, vb1, vb2)
    }
    for (; e < dg; ++e) {
        int2 pa = row[e];
        unsigned sa = (unsigned)pa.x;
        if (sa >= (unsigned)N) continue;
        float na = __int_as_float(pa.y);
        const unsigned short* qa = xw + (size_t)sa * 768 + L * 4;
        ushort4 va0 = *(const ushort4*)qa;
        ushort4 va1 = *(const ushort4*)(qa + 256);
        ushort4 va2 = *(const ushort4*)(qa + 512);
        ACCE(na, va0, va1, va2)
    }

    if (!FINAL) {
        float* o = aggout + (size_t)n * 768 + L * 4;
        *(float4*)o = make_float4(a[0], a[1], a[2], a[3]);
        *(float4*)(o + 256) = make_float4(a[4], a[5], a[6], a[7]);
        *(float4*)(o + 512) = make_float4(a[8], a[9], a[10], a[11]);
    } else {
        float s0 = a[0] + a[4] + a[8];
        float s1 = a[1] + a[5] + a[9];
        float s2 = a[2] + a[6] + a[10];
        float s3 = a[3] + a[7] + a[11];
        s0 += __shfl_xor(s0, 16); s1 += __shfl_xor(s1, 16);
        s2 += __shfl_xor(s2, 16); s3 += __shfl_xor(s3, 16);
        s0 += __shfl_xor(s0, 32); s1 += __shfl_xor(s1, 32);
        s2 += __shfl_xor(s2, 32); s3 += __shfl_xor(s3, 32);
        if (L < 16) {
            const float inv12 = 1.f / 12.f;
            hbuf[nn][L * 4 + 0] = s0 * inv12;
            hbuf[nn][L * 4 + 1] = s1 * inv12;
            hbuf[nn][L * 4 + 2] = s2 * inv12;
            hbuf[nn][L * 4 + 3] = s3 * inv12;
        }
        __syncthreads();
        if (L < 32) {
            float oa = ob[L];
            #pragma unroll
            for (int cc = 0; cc < 64; ++cc)
                oa = fmaf(hbuf[nn][cc], ow[cc * 32 + L], oa);
            dout[(size_t)n * 32 + L] = oa;
        }
    }
}

extern "C" void kernel_launch(void* const* d_in, const int* in_sizes, int n_in,
                              void* d_out, int out_size, void* d_ws, size_t ws_size,
                              hipStream_t stream)
{
    const float* x   = (const float*)d_in[0];
    const int*   ei  = (const int*)d_in[1];
    const float* ew  = (const float*)d_in[2];
    const float* cw1 = (const float*)d_in[3];
    const float* cb1 = (const float*)d_in[4];
    const float* gm1 = (const float*)d_in[5];
    const float* bt1 = (const float*)d_in[6];
    const float* gw1 = (const float*)d_in[7];
    const float* gb1 = (const float*)d_in[8];
    const float* cw2 = (const float*)d_in[9];
    const float* cb2 = (const float*)d_in[10];
    const float* gm2 = (const float*)d_in[11];
    const float* bt2 = (const float*)d_in[12];
    const float* gw2 = (const float*)d_in[13];
    const float* gb2 = (const float*)d_in[14];
    const float* ow  = (const float*)d_in[15];
    const float* ob  = (const float*)d_in[16];

    const int N = in_sizes[0] / (12 * 32);
    const int E = in_sizes[2];

    // workspace layout
    char* p0 = (char*)d_ws;
    char* p = p0;
    float* deg = (float*)p;          p += (size_t)N * 4;
    unsigned* cnt = (unsigned*)p;    p += (size_t)N * 4;   // adjacent to deg: one memset
    float* dis = (float*)p;          p += (size_t)N * 4;
    p = (char*)(((uintptr_t)p + 255) & ~(uintptr_t)255);
    int2* ell = (int2*)p;            p += (size_t)N * MAXDEG * 8;
    p = (char*)(((uintptr_t)p + 255) & ~(uintptr_t)255);
    unsigned short* bufXW = (unsigned short*)p; p += (size_t)N * 768 * 2;  // xw, bf16
    float* bufAgg = (float*)p;                  p += (size_t)N * 768 * 4;  // agg, f32

    const size_t need = (size_t)(p - p0);
    if (ws_size < need) {
        hipMemsetAsync(d_out, 0, (size_t)out_size * 4, stream);   // sentinel
        return;
    }

    hipMemsetAsync(deg, 0, (size_t)N * 8, stream);

    const int eb  = (E + 255) / 256;
    const int nb8 = (N + 7) / 8;
    const int nb4 = (N + 3) / 4;
    k_build_ell<<<eb, 256, 0, stream>>>(ei, ew, deg, cnt, ell, E);
    k_dis<<<(N + 255) / 256, 256, 0, stream>>>(deg, dis, N);
    k_norm<<<(N * MAXDEG + 255) / 256, 256, 0, stream>>>(ell, cnt, dis, N);

    // layer 1: conv+IN+ReLU+GEMM fused (MFMA) -> bufXW (bf16); agg -> bufAgg (f32)
    k_layer_a<32, true ><<<nb8, 512, 0, stream>>>(x, cw1, cb1, gm1, bt1, gw1, bufXW, N);
    k_layer_b<false><<<nb4, 256, 0, stream>>>(bufXW, ell, cnt, dis, gb1, bufAgg, nullptr, nullptr, nullptr, N);
    // layer 2 + fused mean/head
    k_layer_a<64, false><<<nb8, 512, 0, stream>>>(bufAgg, cw2, cb2, gm2, bt2, gw2, bufXW, N);
    k_layer_b<true ><<<nb4, 256, 0, stream>>>(bufXW, ell, cnt, dis, gb2, nullptr, ow, ob, (float*)d_out, N);
}

// Round 11
// 229.585 us; speedup vs baseline: 1.6774x; 1.1224x over previous
//
#include <hip/hip_runtime.h>
#include <hip/hip_bf16.h>
#include <stdint.h>

#define MAXDEG 64

typedef short s16x8 __attribute__((ext_vector_type(8)));
typedef short s16x4 __attribute__((ext_vector_type(4)));
typedef float f32x4 __attribute__((ext_vector_type(4)));

static __device__ __forceinline__ float us2f(unsigned short u) {
    union { float f; unsigned int i; } cv; cv.i = ((unsigned int)u) << 16; return cv.f;
}
static __device__ __forceinline__ unsigned short f2us(float f) {
    __hip_bfloat16 h = __float2bfloat16(f);   // RNE
    return *(unsigned short*)&h;
}

// ---------------- setup: degree + ELL adjacency (incoming edges per dst) ----------------
__global__ void k_build_ell(const int* __restrict__ ei, const float* __restrict__ ew,
                            float* __restrict__ deg, unsigned* __restrict__ cnt,
                            int2* __restrict__ ell, int E)
{
    int e = blockIdx.x * 256 + threadIdx.x;
    if (e >= E) return;
    int s = ei[e], d = ei[E + e];
    float w = ew[e];
    atomicAdd(&deg[d], w);
    unsigned slot = atomicAdd(&cnt[d], 1u);
    if (slot < MAXDEG) ell[(size_t)d * MAXDEG + slot] = make_int2(s, __float_as_int(w));
}

__global__ void k_dis(const float* __restrict__ deg, float* __restrict__ dis, int N)
{
    int i = blockIdx.x * 256 + threadIdx.x;
    if (i < N) dis[i] = rsqrtf(deg[i] + 1.0f);
}

// ---- precompute edge norm dis[src]*w*dis[dst] into ELL payload ----
__global__ void k_norm(int2* __restrict__ ell, const unsigned* __restrict__ cnt,
                       const float* __restrict__ dis, int N)
{
    int idx = blockIdx.x * 256 + threadIdx.x;
    if (idx >= N * MAXDEG) return;
    int n = idx >> 6;               // MAXDEG = 64
    int s = idx & (MAXDEG - 1);
    unsigned dg = cnt[n]; if (dg > MAXDEG) dg = MAXDEG;
    if ((unsigned)s >= dg) return;
    int2 p = ell[idx];
    unsigned sx = (unsigned)p.x;
    float nrm = (sx < (unsigned)N) ? dis[sx] * __int_as_float(p.y) * dis[n] : 0.f;
    ell[idx] = make_int2(p.x, __float_as_int(nrm));
}

// ---------------- layer A (MFMA, conv-as-3-shifted-GEMMs) ------------------------------
// conv:  h[t][c] = sum_kk ( Xpad[t+kk][ci] @ W_kk[ci][c] ),  Xpad rows 0..13 = t=-1..12.
// All LDS tiles at row stride 72 (CIN=32 W: 40): 4-bank spans start 4*(m+q)%32 ->
// uniform 8 words/bank = wave64 b128 floor, no conflicts. A/B fragments are single
// ds_read_b128. IN: bias cancels; rows 12..15 garbage confined to quad 3 -> zero q==3
// stats contributions. A-row reads clamped to 11 (no LDS OOB; C rows 12..15 unused).
// LDS: CIN=64: WT 27648 + gwT 9216 + xh 16128 = 52992 -> 3 blocks/CU.
//      CIN=32: 15360 + 9216 + 16128 = 40704 -> 4 blocks/CU.
template<int CIN, bool FIRST>
__global__ __launch_bounds__(512, 4) void k_layer_a(
    const float* __restrict__ x_in,   // FIRST: [T][N][CIN] f32; else agg [N][768] f32
    const float* __restrict__ cw,     // [64][CIN][3] f32
    const float* __restrict__ cb,     // unused: bias cancels under InstanceNorm
    const float* __restrict__ gm, const float* __restrict__ bt,
    const float* __restrict__ gw,     // [64][64] f32
    unsigned short* __restrict__ xw_out, int N)
{
    constexpr int KT   = CIN / 32;            // conv K-tiles per kk
    constexpr int WSTR = (CIN == 64) ? 72 : 40;  // %8==0 (16B rows), words%32 != 0
    __shared__ __align__(16) short WT[3 * 64 * WSTR];  // WT[kk][c][ci] = cw[c][ci][kk]
    __shared__ __align__(16) short gwT[64 * 72];       // gwT[d][cc] = gw[cc][d]
    __shared__ __align__(16) short xh[8][14 * 72];     // x-pad rows 0..13 / h rows 0..11
    (void)cb;

    const int tid = threadIdx.x;
    const int nn = tid >> 6;
    const int c = tid & 63;          // lane
    const int m = c & 15;            // MFMA 16-index
    const int q = c >> 4;            // quad
    const int mrow = (m < 12) ? m : 11;   // clamped A-row (t)
    int n = blockIdx.x * 8 + nn;
    if (n >= N) n = N - 1;

    // ---- stage conv weights: WT[kk][cc][ci] = cw[(cc*CIN+ci)*3 + kk] (bf16) ----
    for (int g = tid; g < 3 * 64 * CIN; g += 512) {
        int kk = g / (64 * CIN);
        int r = g - kk * 64 * CIN;
        int cc = r / CIN, ci = r - cc * CIN;
        WT[kk * (64 * WSTR) + cc * WSTR + ci] = (short)f2us(cw[(cc * CIN + ci) * 3 + kk]);
    }
    // ---- stage gw transposed ----
    for (int g = tid; g < 4096; g += 512) {
        int cc = g >> 6, d = g & 63;
        gwT[d * 72 + cc] = (short)f2us(gw[g]);
    }
    // ---- stage x tile rows t=-1..12 -> rows 0..13, row stride 72 ----
    if (FIRST) {
        #pragma unroll
        for (int it = 0; it < (12 * CIN) / 64; ++it) {
            int i = it * 64 + c;
            int t = i / CIN, ci = i - t * CIN;
            xh[nn][(t + 1) * 72 + ci] = (short)f2us(x_in[((size_t)t * N + n) * CIN + ci]);
        }
    } else {
        const float* src = x_in + (size_t)n * 768;
        #pragma unroll
        for (int j3 = 0; j3 < 3; ++j3) {
            int idx = j3 * 256 + c * 4;
            float4 v = *(const float4*)(src + idx);
            int t = idx >> 6, ci = idx & 63;
            s16x4 s4 = { (short)f2us(v.x), (short)f2us(v.y), (short)f2us(v.z), (short)f2us(v.w) };
            *(s16x4*)&xh[nn][(t + 1) * 72 + ci] = s4;
        }
    }
    if (c < CIN) { xh[nn][c] = 0; xh[nn][13 * 72 + c] = 0; }
    __syncthreads();

    // ---- conv: 3 shifted GEMMs, all-b128 fragments ----
    f32x4 acc[4];
    #pragma unroll
    for (int nt = 0; nt < 4; ++nt) acc[nt] = (f32x4){0.f, 0.f, 0.f, 0.f};
    #pragma unroll
    for (int kk = 0; kk < 3; ++kk) {
        #pragma unroll
        for (int kt = 0; kt < KT; ++kt) {
            s16x8 aA = *(const s16x8*)&xh[nn][(mrow + kk) * 72 + kt * 32 + q * 8];
            #pragma unroll
            for (int nt = 0; nt < 4; ++nt) {
                s16x8 bB = *(const s16x8*)&WT[kk * (64 * WSTR) + (nt * 16 + m) * WSTR + kt * 32 + q * 8];
                acc[nt] = __builtin_amdgcn_mfma_f32_16x16x32_bf16(aA, bB, acc[nt], 0, 0, 0);
            }
        }
    }

    // ---- InstanceNorm over T + ReLU; h -> LDS rows 0..11 (overwrites x rows 0..11) ----
    #pragma unroll
    for (int nt = 0; nt < 4; ++nt) {
        float s  = acc[nt][0] + acc[nt][1] + acc[nt][2] + acc[nt][3];
        float s2 = acc[nt][0] * acc[nt][0] + acc[nt][1] * acc[nt][1]
                 + acc[nt][2] * acc[nt][2] + acc[nt][3] * acc[nt][3];
        if (q == 3) { s = 0.f; s2 = 0.f; }    // rows 12..15 are garbage -> exclude
        s  += __shfl_xor(s, 16);  s  += __shfl_xor(s, 32);
        s2 += __shfl_xor(s2, 16); s2 += __shfl_xor(s2, 32);
        const float mu  = s * (1.f / 12.f);
        const float var = s2 * (1.f / 12.f) - mu * mu;
        const float scn = rsqrtf(var + 1e-5f) * gm[nt * 16 + m];
        const float sbn = bt[nt * 16 + m];
        if (q < 3) {
            #pragma unroll
            for (int reg = 0; reg < 4; ++reg) {
                float h = fmaf(acc[nt][reg] - mu, scn, sbn);
                h = h > 0.f ? h : 0.f;
                xh[nn][(q * 4 + reg) * 72 + nt * 16 + m] = (short)f2us(h);
            }
        }
    }

    // ---- gemm2: xw = h @ gw (b128 fragments) ----
    s16x8 a2[2];
    #pragma unroll
    for (int kt2 = 0; kt2 < 2; ++kt2)
        a2[kt2] = *(const s16x8*)&xh[nn][mrow * 72 + kt2 * 32 + q * 8];
    f32x4 acc2[4];
    #pragma unroll
    for (int nt = 0; nt < 4; ++nt) acc2[nt] = (f32x4){0.f, 0.f, 0.f, 0.f};
    #pragma unroll
    for (int nt = 0; nt < 4; ++nt) {
        #pragma unroll
        for (int kt2 = 0; kt2 < 2; ++kt2) {
            s16x8 b2 = *(const s16x8*)&gwT[(nt * 16 + m) * 72 + kt2 * 32 + q * 8];
            acc2[nt] = __builtin_amdgcn_mfma_f32_16x16x32_bf16(a2[kt2], b2, acc2[nt], 0, 0, 0);
        }
    }

    // ---- store xw rows t<12 (C-layout: row=q*4+reg, col=nt*16+m) ----
    unsigned short* dst = xw_out + (size_t)n * 768;
    if (q < 3) {
        #pragma unroll
        for (int nt = 0; nt < 4; ++nt)
            #pragma unroll
            for (int reg = 0; reg < 4; ++reg)
                dst[(q * 4 + reg) * 64 + nt * 16 + m] = f2us(acc2[nt][reg]);
    }
}

// ---------------- layer B: ELL aggregation (+ fused mean_t + 64x32 head if FINAL) ------
#define ACCE(NRM, V0, V1, V2)                                                          \
    a[0] = fmaf(NRM, us2f(V0.x), a[0]);  a[1] = fmaf(NRM, us2f(V0.y), a[1]);           \
    a[2] = fmaf(NRM, us2f(V0.z), a[2]);  a[3] = fmaf(NRM, us2f(V0.w), a[3]);           \
    a[4] = fmaf(NRM, us2f(V1.x), a[4]);  a[5] = fmaf(NRM, us2f(V1.y), a[5]);           \
    a[6] = fmaf(NRM, us2f(V1.z), a[6]);  a[7] = fmaf(NRM, us2f(V1.w), a[7]);           \
    a[8] = fmaf(NRM, us2f(V2.x), a[8]);  a[9] = fmaf(NRM, us2f(V2.y), a[9]);           \
    a[10] = fmaf(NRM, us2f(V2.z), a[10]); a[11] = fmaf(NRM, us2f(V2.w), a[11]);

template<bool FINAL>
__global__ __launch_bounds__(256) void k_layer_b(
    const unsigned short* __restrict__ xw, const int2* __restrict__ ell,
    const unsigned* __restrict__ cnt, const float* __restrict__ dis,
    const float* __restrict__ gb, float* __restrict__ aggout,
    const float* __restrict__ ow, const float* __restrict__ ob,
    float* __restrict__ dout, int N)
{
    __shared__ __align__(16) float hbuf[4][64];
    const int tid = threadIdx.x;
    const int nn = tid >> 6, L = tid & 63;
    int n = blockIdx.x * 4 + nn;
    if (n >= N) n = N - 1;
    const float dn = dis[n];
    const float d2 = dn * dn;

    float a[12];
    {   // self loop: d2 * xw[n] + gb
        const unsigned short* self = xw + (size_t)n * 768 + L * 4;
        ushort4 v0 = *(const ushort4*)self;
        ushort4 v1 = *(const ushort4*)(self + 256);
        ushort4 v2 = *(const ushort4*)(self + 512);
        const int c0 = (L * 4) & 63;
        const float g0 = gb[c0], g1 = gb[c0 + 1], g2 = gb[c0 + 2], g3 = gb[c0 + 3];
        a[0] = fmaf(d2, us2f(v0.x), g0); a[1] = fmaf(d2, us2f(v0.y), g1);
        a[2] = fmaf(d2, us2f(v0.z), g2); a[3] = fmaf(d2, us2f(v0.w), g3);
        a[4] = fmaf(d2, us2f(v1.x), g0); a[5] = fmaf(d2, us2f(v1.y), g1);
        a[6] = fmaf(d2, us2f(v1.z), g2); a[7] = fmaf(d2, us2f(v1.w), g3);
        a[8] = fmaf(d2, us2f(v2.x), g0); a[9] = fmaf(d2, us2f(v2.y), g1);
        a[10] = fmaf(d2, us2f(v2.z), g2); a[11] = fmaf(d2, us2f(v2.w), g3);
    }

    unsigned dg = cnt[n];
    if (dg > MAXDEG) dg = MAXDEG;
    const int2* row = ell + (size_t)n * MAXDEG;
    unsigned e = 0;
    for (; e + 2 <= dg; e += 2) {
        int2 pa = row[e], pb = row[e + 1];
        unsigned sa = (unsigned)pa.x, sb = (unsigned)pb.x;
        if (sa >= (unsigned)N || sb >= (unsigned)N) break;   // defensive
        float na = __int_as_float(pa.y);                     // precomputed norm
        float nb = __int_as_float(pb.y);
        const unsigned short* qa = xw + (size_t)sa * 768 + L * 4;
        const unsigned short* qb = xw + (size_t)sb * 768 + L * 4;
        ushort4 va0 = *(const ushort4*)qa;
        ushort4 va1 = *(const ushort4*)(qa + 256);
        ushort4 va2 = *(const ushort4*)(qa + 512);
        ushort4 vb0 = *(const ushort4*)qb;
        ushort4 vb1 = *(const ushort4*)(qb + 256);
        ushort4 vb2 = *(const ushort4*)(qb + 512);
        ACCE(na, va0, va1, va2)
        ACCE(nb, vb0, vb1, vb2)
    }
    for (; e < dg; ++e) {
        int2 pa = row[e];
        unsigned sa = (unsigned)pa.x;
        if (sa >= (unsigned)N) continue;
        float na = __int_as_float(pa.y);
        const unsigned short* qa = xw + (size_t)sa * 768 + L * 4;
        ushort4 va0 = *(const ushort4*)qa;
        ushort4 va1 = *(const ushort4*)(qa + 256);
        ushort4 va2 = *(const ushort4*)(qa + 512);
        ACCE(na, va0, va1, va2)
    }

    if (!FINAL) {
        float* o = aggout + (size_t)n * 768 + L * 4;
        *(float4*)o = make_float4(a[0], a[1], a[2], a[3]);
        *(float4*)(o + 256) = make_float4(a[4], a[5], a[6], a[7]);
        *(float4*)(o + 512) = make_float4(a[8], a[9], a[10], a[11]);
    } else {
        float s0 = a[0] + a[4] + a[8];
        float s1 = a[1] + a[5] + a[9];
        float s2 = a[2] + a[6] + a[10];
        float s3 = a[3] + a[7] + a[11];
        s0 += __shfl_xor(s0, 16); s1 += __shfl_xor(s1, 16);
        s2 += __shfl_xor(s2, 16); s3 += __shfl_xor(s3, 16);
        s0 += __shfl_xor(s0, 32); s1 += __shfl_xor(s1, 32);
        s2 += __shfl_xor(s2, 32); s3 += __shfl_xor(s3, 32);
        if (L < 16) {
            const float inv12 = 1.f / 12.f;
            hbuf[nn][L * 4 + 0] = s0 * inv12;
            hbuf[nn][L * 4 + 1] = s1 * inv12;
            hbuf[nn][L * 4 + 2] = s2 * inv12;
            hbuf[nn][L * 4 + 3] = s3 * inv12;
        }
        __syncthreads();
        if (L < 32) {
            float oa = ob[L];
            #pragma unroll
            for (int cc = 0; cc < 64; ++cc)
                oa = fmaf(hbuf[nn][cc], ow[cc * 32 + L], oa);
            dout[(size_t)n * 32 + L] = oa;
        }
    }
}

extern "C" void kernel_launch(void* const* d_in, const int* in_sizes, int n_in,
                              void* d_out, int out_size, void* d_ws, size_t ws_size,
                              hipStream_t stream)
{
    const float* x   = (const float*)d_in[0];
    const int*   ei  = (const int*)d_in[1];
    const float* ew  = (const float*)d_in[2];
    const float* cw1 = (const float*)d_in[3];
    const float* cb1 = (const float*)d_in[4];
    const float* gm1 = (const float*)d_in[5];
    const float* bt1 = (const float*)d_in[6];
    const float* gw1 = (const float*)d_in[7];
    const float* gb1 = (const float*)d_in[8];
    const float* cw2 = (const float*)d_in[9];
    const float* cb2 = (const float*)d_in[10];
    const float* gm2 = (const float*)d_in[11];
    const float* bt2 = (const float*)d_in[12];
    const float* gw2 = (const float*)d_in[13];
    const float* gb2 = (const float*)d_in[14];
    const float* ow  = (const float*)d_in[15];
    const float* ob  = (const float*)d_in[16];

    const int N = in_sizes[0] / (12 * 32);
    const int E = in_sizes[2];

    // workspace layout
    char* p0 = (char*)d_ws;
    char* p = p0;
    float* deg = (float*)p;          p += (size_t)N * 4;
    unsigned* cnt = (unsigned*)p;    p += (size_t)N * 4;   // adjacent to deg: one memset
    float* dis = (float*)p;          p += (size_t)N * 4;
    p = (char*)(((uintptr_t)p + 255) & ~(uintptr_t)255);
    int2* ell = (int2*)p;            p += (size_t)N * MAXDEG * 8;
    p = (char*)(((uintptr_t)p + 255) & ~(uintptr_t)255);
    unsigned short* bufXW = (unsigned short*)p; p += (size_t)N * 768 * 2;  // xw, bf16
    float* bufAgg = (float*)p;                  p += (size_t)N * 768 * 4;  // agg, f32

    const size_t need = (size_t)(p - p0);
    if (ws_size < need) {
        hipMemsetAsync(d_out, 0, (size_t)out_size * 4, stream);   // sentinel
        return;
    }

    hipMemsetAsync(deg, 0, (size_t)N * 8, stream);

    const int eb  = (E + 255) / 256;
    const int nb8 = (N + 7) / 8;
    const int nb4 = (N + 3) / 4;
    k_build_ell<<<eb, 256, 0, stream>>>(ei, ew, deg, cnt, ell, E);
    k_dis<<<(N + 255) / 256, 256, 0, stream>>>(deg, dis, N);
    k_norm<<<(N * MAXDEG + 255) / 256, 256, 0, stream>>>(ell, cnt, dis, N);

    // layer 1: conv+IN+ReLU+GEMM fused (MFMA) -> bufXW (bf16); agg -> bufAgg (f32)
    k_layer_a<32, true ><<<nb8, 512, 0, stream>>>(x, cw1, cb1, gm1, bt1, gw1, bufXW, N);
    k_layer_b<false><<<nb4, 256, 0, stream>>>(bufXW, ell, cnt, dis, gb1, bufAgg, nullptr, nullptr, nullptr, N);
    // layer 2 + fused mean/head
    k_layer_a<64, false><<<nb8, 512, 0, stream>>>(bufAgg, cw2, cb2, gm2, bt2, gw2, bufXW, N);
    k_layer_b<true ><<<nb4, 256, 0, stream>>>(bufXW, ell, cnt, dis, gb2, nullptr, ow, ob, (float*)d_out, N);
}

// Round 12
// 214.518 us; speedup vs baseline: 1.7952x; 1.0702x over previous
//
#include <hip/hip_runtime.h>
#include <hip/hip_bf16.h>
#include <stdint.h>

#define MAXDEG 64

typedef short s16x8 __attribute__((ext_vector_type(8)));
typedef short s16x4 __attribute__((ext_vector_type(4)));
typedef float f32x4 __attribute__((ext_vector_type(4)));

static __device__ __forceinline__ float us2f(unsigned short u) {
    union { float f; unsigned int i; } cv; cv.i = ((unsigned int)u) << 16; return cv.f;
}
static __device__ __forceinline__ unsigned short f2us(float f) {
    __hip_bfloat16 h = __float2bfloat16(f);   // RNE
    return *(unsigned short*)&h;
}

// ---------------- setup: degree + ELL adjacency (incoming edges per dst) ----------------
__global__ void k_build_ell(const int* __restrict__ ei, const float* __restrict__ ew,
                            float* __restrict__ deg, unsigned* __restrict__ cnt,
                            int2* __restrict__ ell, int E)
{
    int e = blockIdx.x * 256 + threadIdx.x;
    if (e >= E) return;
    int s = ei[e], d = ei[E + e];
    float w = ew[e];
    atomicAdd(&deg[d], w);
    unsigned slot = atomicAdd(&cnt[d], 1u);
    if (slot < MAXDEG) ell[(size_t)d * MAXDEG + slot] = make_int2(s, __float_as_int(w));
}

__global__ void k_dis(const float* __restrict__ deg, float* __restrict__ dis, int N)
{
    int i = blockIdx.x * 256 + threadIdx.x;
    if (i < N) dis[i] = rsqrtf(deg[i] + 1.0f);
}

// ---- precompute edge norm dis[src]*w*dis[dst] into ELL payload ----
__global__ void k_norm(int2* __restrict__ ell, const unsigned* __restrict__ cnt,
                       const float* __restrict__ dis, int N)
{
    int idx = blockIdx.x * 256 + threadIdx.x;
    if (idx >= N * MAXDEG) return;
    int n = idx >> 6;               // MAXDEG = 64
    int s = idx & (MAXDEG - 1);
    unsigned dg = cnt[n]; if (dg > MAXDEG) dg = MAXDEG;
    if ((unsigned)s >= dg) return;
    int2 p = ell[idx];
    unsigned sx = (unsigned)p.x;
    float nrm = (sx < (unsigned)N) ? dis[sx] * __int_as_float(p.y) * dis[n] : 0.f;
    ell[idx] = make_int2(p.x, __float_as_int(nrm));
}

// lane-L edge gather: 3 x ushort4 from a 1536B bf16 row + 12 fma
#define ACCE(NRM, V0, V1, V2)                                                          \
    a[0] = fmaf(NRM, us2f(V0.x), a[0]);  a[1] = fmaf(NRM, us2f(V0.y), a[1]);           \
    a[2] = fmaf(NRM, us2f(V0.z), a[2]);  a[3] = fmaf(NRM, us2f(V0.w), a[3]);           \
    a[4] = fmaf(NRM, us2f(V1.x), a[4]);  a[5] = fmaf(NRM, us2f(V1.y), a[5]);           \
    a[6] = fmaf(NRM, us2f(V1.z), a[6]);  a[7] = fmaf(NRM, us2f(V1.w), a[7]);           \
    a[8] = fmaf(NRM, us2f(V2.x), a[8]);  a[9] = fmaf(NRM, us2f(V2.y), a[9]);           \
    a[10] = fmaf(NRM, us2f(V2.z), a[10]); a[11] = fmaf(NRM, us2f(V2.w), a[11]);

#define EDGE_GATHER(P)                                                      \
    {                                                                       \
        unsigned sx = (unsigned)(P).x;                                      \
        if (sx >= (unsigned)N) sx = 0;        /* nrm already 0 (k_norm) */  \
        float nrm = __int_as_float((P).y);                                  \
        const unsigned short* qp = xw_in + (size_t)sx * 768 + L * 4;        \
        ushort4 w0 = *(const ushort4*)qp;                                   \
        ushort4 w1 = *(const ushort4*)(qp + 256);                           \
        ushort4 w2 = *(const ushort4*)(qp + 512);                           \
        ACCE(nrm, w0, w1, w2)                                               \
    }

// ---------------- layer A (MFMA, conv-as-3-shifted-GEMMs), layer-1 only ---------------
template<int CIN>
__global__ __launch_bounds__(512, 4) void k_layer_a(
    const float* __restrict__ x_in,   // [T][N][CIN] f32
    const float* __restrict__ cw,     // [64][CIN][3] f32
    const float* __restrict__ gm, const float* __restrict__ bt,
    const float* __restrict__ gw,     // [64][64] f32
    unsigned short* __restrict__ xw_out, int N)
{
    constexpr int KT   = CIN / 32;
    constexpr int WSTR = (CIN == 64) ? 72 : 40;
    __shared__ __align__(16) short WT[3 * 64 * WSTR];  // WT[kk][c][ci]
    __shared__ __align__(16) short gwT[64 * 72];       // gwT[d][cc]
    __shared__ __align__(16) short xh[8][14 * 72];

    const int tid = threadIdx.x;
    const int nn = tid >> 6;
    const int c = tid & 63;
    const int m = c & 15;
    const int q = c >> 4;
    const int mrow = (m < 12) ? m : 11;
    int n = blockIdx.x * 8 + nn;
    if (n >= N) n = N - 1;

    for (int g = tid; g < 3 * 64 * CIN; g += 512) {
        int kk = g / (64 * CIN);
        int r = g - kk * 64 * CIN;
        int cc = r / CIN, ci = r - cc * CIN;
        WT[kk * (64 * WSTR) + cc * WSTR + ci] = (short)f2us(cw[(cc * CIN + ci) * 3 + kk]);
    }
    for (int g = tid; g < 4096; g += 512) {
        int cc = g >> 6, d = g & 63;
        gwT[d * 72 + cc] = (short)f2us(gw[g]);
    }
    #pragma unroll
    for (int it = 0; it < (12 * CIN) / 64; ++it) {
        int i = it * 64 + c;
        int t = i / CIN, ci = i - t * CIN;
        xh[nn][(t + 1) * 72 + ci] = (short)f2us(x_in[((size_t)t * N + n) * CIN + ci]);
    }
    if (c < CIN) { xh[nn][c] = 0; xh[nn][13 * 72 + c] = 0; }
    __syncthreads();

    f32x4 acc[4];
    #pragma unroll
    for (int nt = 0; nt < 4; ++nt) acc[nt] = (f32x4){0.f, 0.f, 0.f, 0.f};
    #pragma unroll
    for (int kk = 0; kk < 3; ++kk) {
        #pragma unroll
        for (int kt = 0; kt < KT; ++kt) {
            s16x8 aA = *(const s16x8*)&xh[nn][(mrow + kk) * 72 + kt * 32 + q * 8];
            #pragma unroll
            for (int nt = 0; nt < 4; ++nt) {
                s16x8 bB = *(const s16x8*)&WT[kk * (64 * WSTR) + (nt * 16 + m) * WSTR + kt * 32 + q * 8];
                acc[nt] = __builtin_amdgcn_mfma_f32_16x16x32_bf16(aA, bB, acc[nt], 0, 0, 0);
            }
        }
    }

    #pragma unroll
    for (int nt = 0; nt < 4; ++nt) {
        float s  = acc[nt][0] + acc[nt][1] + acc[nt][2] + acc[nt][3];
        float s2 = acc[nt][0] * acc[nt][0] + acc[nt][1] * acc[nt][1]
                 + acc[nt][2] * acc[nt][2] + acc[nt][3] * acc[nt][3];
        if (q == 3) { s = 0.f; s2 = 0.f; }
        s  += __shfl_xor(s, 16);  s  += __shfl_xor(s, 32);
        s2 += __shfl_xor(s2, 16); s2 += __shfl_xor(s2, 32);
        const float mu  = s * (1.f / 12.f);
        const float var = s2 * (1.f / 12.f) - mu * mu;
        const float scn = rsqrtf(var + 1e-5f) * gm[nt * 16 + m];
        const float sbn = bt[nt * 16 + m];
        if (q < 3) {
            #pragma unroll
            for (int reg = 0; reg < 4; ++reg) {
                float h = fmaf(acc[nt][reg] - mu, scn, sbn);
                h = h > 0.f ? h : 0.f;
                xh[nn][(q * 4 + reg) * 72 + nt * 16 + m] = (short)f2us(h);
            }
        }
    }

    s16x8 a2[2];
    #pragma unroll
    for (int kt2 = 0; kt2 < 2; ++kt2)
        a2[kt2] = *(const s16x8*)&xh[nn][mrow * 72 + kt2 * 32 + q * 8];
    f32x4 acc2[4];
    #pragma unroll
    for (int nt = 0; nt < 4; ++nt) acc2[nt] = (f32x4){0.f, 0.f, 0.f, 0.f};
    #pragma unroll
    for (int nt = 0; nt < 4; ++nt) {
        #pragma unroll
        for (int kt2 = 0; kt2 < 2; ++kt2) {
            s16x8 b2 = *(const s16x8*)&gwT[(nt * 16 + m) * 72 + kt2 * 32 + q * 8];
            acc2[nt] = __builtin_amdgcn_mfma_f32_16x16x32_bf16(a2[kt2], b2, acc2[nt], 0, 0, 0);
        }
    }

    unsigned short* dst = xw_out + (size_t)n * 768;
    if (q < 3) {
        #pragma unroll
        for (int nt = 0; nt < 4; ++nt)
            #pragma unroll
            for (int reg = 0; reg < 4; ++reg)
                dst[(q * 4 + reg) * 64 + nt * 16 + m] = f2us(acc2[nt][reg]);
    }
}

// ---------------- fused: ELL aggregation (layer-1 GCN) + layer-2 conv/IN/ReLU/gemm -----
// One wave per node. Gather agg into registers (never touches HBM), pack bf16 into the
// wave-private xh tile, then the layer-2 MFMA pipeline. Same roundings as the split
// version (agg was staged via f2us before too).
__global__ __launch_bounds__(512, 4) void k_gather_a(
    const unsigned short* __restrict__ xw_in,   // [N][768] bf16 (layer-1 xw)
    const int2* __restrict__ ell, const unsigned* __restrict__ cnt,
    const float* __restrict__ dis, const float* __restrict__ gb,   // gb1
    const float* __restrict__ cw,   // cw2 [64][64][3]
    const float* __restrict__ gm, const float* __restrict__ bt,    // gm2, bt2
    const float* __restrict__ gw,   // gw2 [64][64]
    unsigned short* __restrict__ xw_out, int N)
{
    constexpr int WSTR = 72;
    __shared__ __align__(16) short WT[3 * 64 * WSTR];
    __shared__ __align__(16) short gwT[64 * 72];
    __shared__ __align__(16) short xh[8][14 * 72];

    const int tid = threadIdx.x;
    const int nn = tid >> 6;
    const int L = tid & 63;
    const int m = L & 15;
    const int q = L >> 4;
    const int mrow = (m < 12) ? m : 11;
    int n = blockIdx.x * 8 + nn;
    if (n >= N) n = N - 1;

    // stage layer-2 weights
    for (int g = tid; g < 3 * 64 * 64; g += 512) {
        int kk = g >> 12;                 // /4096
        int r = g & 4095;
        int cc = r >> 6, ci = r & 63;
        WT[kk * (64 * WSTR) + cc * WSTR + ci] = (short)f2us(cw[(cc * 64 + ci) * 3 + kk]);
    }
    for (int g = tid; g < 4096; g += 512) {
        int cc = g >> 6, d = g & 63;
        gwT[d * 72 + cc] = (short)f2us(gw[g]);
    }
    xh[nn][L] = 0; xh[nn][13 * 72 + L] = 0;    // conv zero-pad rows
    __syncthreads();

    // ---- gather: agg[t][c] for this node, in registers ----
    const float dn = dis[n];
    const float d2 = dn * dn;
    float a[12];
    {
        const unsigned short* self = xw_in + (size_t)n * 768 + L * 4;
        ushort4 v0 = *(const ushort4*)self;
        ushort4 v1 = *(const ushort4*)(self + 256);
        ushort4 v2 = *(const ushort4*)(self + 512);
        const int c0 = (L * 4) & 63;
        const float g0 = gb[c0], g1 = gb[c0 + 1], g2 = gb[c0 + 2], g3 = gb[c0 + 3];
        a[0] = fmaf(d2, us2f(v0.x), g0); a[1] = fmaf(d2, us2f(v0.y), g1);
        a[2] = fmaf(d2, us2f(v0.z), g2); a[3] = fmaf(d2, us2f(v0.w), g3);
        a[4] = fmaf(d2, us2f(v1.x), g0); a[5] = fmaf(d2, us2f(v1.y), g1);
        a[6] = fmaf(d2, us2f(v1.z), g2); a[7] = fmaf(d2, us2f(v1.w), g3);
        a[8] = fmaf(d2, us2f(v2.x), g0); a[9] = fmaf(d2, us2f(v2.y), g1);
        a[10] = fmaf(d2, us2f(v2.z), g2); a[11] = fmaf(d2, us2f(v2.w), g3);
    }
    unsigned dg = cnt[n]; if (dg > MAXDEG) dg = MAXDEG;
    const int2* row = ell + (size_t)n * MAXDEG;
    unsigned e = 0;
    for (; e + 4 <= dg; e += 4) {
        int2 p0 = row[e], p1 = row[e + 1], p2 = row[e + 2], p3 = row[e + 3];
        EDGE_GATHER(p0) EDGE_GATHER(p1) EDGE_GATHER(p2) EDGE_GATHER(p3)
    }
    for (; e < dg; ++e) { int2 p0 = row[e]; EDGE_GATHER(p0) }

    // ---- pack agg (bf16) into xh rows 1..12: lane L comp m -> t = j*4+q, ci = (4L+m)&63
    #pragma unroll
    for (int j = 0; j < 3; ++j) {
        s16x4 s4 = { (short)f2us(a[j * 4 + 0]), (short)f2us(a[j * 4 + 1]),
                     (short)f2us(a[j * 4 + 2]), (short)f2us(a[j * 4 + 3]) };
        *(s16x4*)&xh[nn][(j * 4 + q + 1) * 72 + ((L * 4) & 63)] = s4;
    }

    // ---- layer-2 conv (3 shifted GEMMs) ----
    f32x4 acc[4];
    #pragma unroll
    for (int nt = 0; nt < 4; ++nt) acc[nt] = (f32x4){0.f, 0.f, 0.f, 0.f};
    #pragma unroll
    for (int kk = 0; kk < 3; ++kk) {
        #pragma unroll
        for (int kt = 0; kt < 2; ++kt) {
            s16x8 aA = *(const s16x8*)&xh[nn][(mrow + kk) * 72 + kt * 32 + q * 8];
            #pragma unroll
            for (int nt = 0; nt < 4; ++nt) {
                s16x8 bB = *(const s16x8*)&WT[kk * (64 * WSTR) + (nt * 16 + m) * WSTR + kt * 32 + q * 8];
                acc[nt] = __builtin_amdgcn_mfma_f32_16x16x32_bf16(aA, bB, acc[nt], 0, 0, 0);
            }
        }
    }

    // ---- InstanceNorm + ReLU -> xh rows 0..11 ----
    #pragma unroll
    for (int nt = 0; nt < 4; ++nt) {
        float s  = acc[nt][0] + acc[nt][1] + acc[nt][2] + acc[nt][3];
        float s2 = acc[nt][0] * acc[nt][0] + acc[nt][1] * acc[nt][1]
                 + acc[nt][2] * acc[nt][2] + acc[nt][3] * acc[nt][3];
        if (q == 3) { s = 0.f; s2 = 0.f; }
        s  += __shfl_xor(s, 16);  s  += __shfl_xor(s, 32);
        s2 += __shfl_xor(s2, 16); s2 += __shfl_xor(s2, 32);
        const float mu  = s * (1.f / 12.f);
        const float var = s2 * (1.f / 12.f) - mu * mu;
        const float scn = rsqrtf(var + 1e-5f) * gm[nt * 16 + m];
        const float sbn = bt[nt * 16 + m];
        if (q < 3) {
            #pragma unroll
            for (int reg = 0; reg < 4; ++reg) {
                float h = fmaf(acc[nt][reg] - mu, scn, sbn);
                h = h > 0.f ? h : 0.f;
                xh[nn][(q * 4 + reg) * 72 + nt * 16 + m] = (short)f2us(h);
            }
        }
    }

    // ---- gemm2: xw2 = h @ gw2 ----
    s16x8 a2[2];
    #pragma unroll
    for (int kt2 = 0; kt2 < 2; ++kt2)
        a2[kt2] = *(const s16x8*)&xh[nn][mrow * 72 + kt2 * 32 + q * 8];
    f32x4 acc2[4];
    #pragma unroll
    for (int nt = 0; nt < 4; ++nt) acc2[nt] = (f32x4){0.f, 0.f, 0.f, 0.f};
    #pragma unroll
    for (int nt = 0; nt < 4; ++nt) {
        #pragma unroll
        for (int kt2 = 0; kt2 < 2; ++kt2) {
            s16x8 b2 = *(const s16x8*)&gwT[(nt * 16 + m) * 72 + kt2 * 32 + q * 8];
            acc2[nt] = __builtin_amdgcn_mfma_f32_16x16x32_bf16(a2[kt2], b2, acc2[nt], 0, 0, 0);
        }
    }

    unsigned short* dst = xw_out + (size_t)n * 768;
    if (q < 3) {
        #pragma unroll
        for (int nt = 0; nt < 4; ++nt)
            #pragma unroll
            for (int reg = 0; reg < 4; ++reg)
                dst[(q * 4 + reg) * 64 + nt * 16 + m] = f2us(acc2[nt][reg]);
    }
}

// ---------------- final: ELL aggregation + mean_t + 64x32 head --------------------------
__global__ __launch_bounds__(256) void k_final(
    const unsigned short* __restrict__ xw_in, const int2* __restrict__ ell,
    const unsigned* __restrict__ cnt, const float* __restrict__ dis,
    const float* __restrict__ gb,
    const float* __restrict__ ow, const float* __restrict__ ob,
    float* __restrict__ dout, int N)
{
    __shared__ __align__(16) float hbuf[4][64];
    const int tid = threadIdx.x;
    const int nn = tid >> 6, L = tid & 63;
    int n = blockIdx.x * 4 + nn;
    if (n >= N) n = N - 1;
    const float dn = dis[n];
    const float d2 = dn * dn;

    float a[12];
    {
        const unsigned short* self = xw_in + (size_t)n * 768 + L * 4;
        ushort4 v0 = *(const ushort4*)self;
        ushort4 v1 = *(const ushort4*)(self + 256);
        ushort4 v2 = *(const ushort4*)(self + 512);
        const int c0 = (L * 4) & 63;
        const float g0 = gb[c0], g1 = gb[c0 + 1], g2 = gb[c0 + 2], g3 = gb[c0 + 3];
        a[0] = fmaf(d2, us2f(v0.x), g0); a[1] = fmaf(d2, us2f(v0.y), g1);
        a[2] = fmaf(d2, us2f(v0.z), g2); a[3] = fmaf(d2, us2f(v0.w), g3);
        a[4] = fmaf(d2, us2f(v1.x), g0); a[5] = fmaf(d2, us2f(v1.y), g1);
        a[6] = fmaf(d2, us2f(v1.z), g2); a[7] = fmaf(d2, us2f(v1.w), g3);
        a[8] = fmaf(d2, us2f(v2.x), g0); a[9] = fmaf(d2, us2f(v2.y), g1);
        a[10] = fmaf(d2, us2f(v2.z), g2); a[11] = fmaf(d2, us2f(v2.w), g3);
    }

    unsigned dg = cnt[n]; if (dg > MAXDEG) dg = MAXDEG;
    const int2* row = ell + (size_t)n * MAXDEG;
    unsigned e = 0;
    for (; e + 4 <= dg; e += 4) {
        int2 p0 = row[e], p1 = row[e + 1], p2 = row[e + 2], p3 = row[e + 3];
        EDGE_GATHER(p0) EDGE_GATHER(p1) EDGE_GATHER(p2) EDGE_GATHER(p3)
    }
    for (; e < dg; ++e) { int2 p0 = row[e]; EDGE_GATHER(p0) }

    // mean over T then 64x32 head
    float s0 = a[0] + a[4] + a[8];
    float s1 = a[1] + a[5] + a[9];
    float s2 = a[2] + a[6] + a[10];
    float s3 = a[3] + a[7] + a[11];
    s0 += __shfl_xor(s0, 16); s1 += __shfl_xor(s1, 16);
    s2 += __shfl_xor(s2, 16); s3 += __shfl_xor(s3, 16);
    s0 += __shfl_xor(s0, 32); s1 += __shfl_xor(s1, 32);
    s2 += __shfl_xor(s2, 32); s3 += __shfl_xor(s3, 32);
    if (L < 16) {
        const float inv12 = 1.f / 12.f;
        hbuf[nn][L * 4 + 0] = s0 * inv12;
        hbuf[nn][L * 4 + 1] = s1 * inv12;
        hbuf[nn][L * 4 + 2] = s2 * inv12;
        hbuf[nn][L * 4 + 3] = s3 * inv12;
    }
    __syncthreads();
    if (L < 32) {
        float oa = ob[L];
        #pragma unroll
        for (int cc = 0; cc < 64; ++cc)
            oa = fmaf(hbuf[nn][cc], ow[cc * 32 + L], oa);
        dout[(size_t)n * 32 + L] = oa;
    }
}

extern "C" void kernel_launch(void* const* d_in, const int* in_sizes, int n_in,
                              void* d_out, int out_size, void* d_ws, size_t ws_size,
                              hipStream_t stream)
{
    const float* x   = (const float*)d_in[0];
    const int*   ei  = (const int*)d_in[1];
    const float* ew  = (const float*)d_in[2];
    const float* cw1 = (const float*)d_in[3];
    const float* gm1 = (const float*)d_in[5];
    const float* bt1 = (const float*)d_in[6];
    const float* gw1 = (const float*)d_in[7];
    const float* gb1 = (const float*)d_in[8];
    const float* cw2 = (const float*)d_in[9];
    const float* gm2 = (const float*)d_in[11];
    const float* bt2 = (const float*)d_in[12];
    const float* gw2 = (const float*)d_in[13];
    const float* gb2 = (const float*)d_in[14];
    const float* ow  = (const float*)d_in[15];
    const float* ob  = (const float*)d_in[16];

    const int N = in_sizes[0] / (12 * 32);
    const int E = in_sizes[2];

    // workspace layout
    char* p0 = (char*)d_ws;
    char* p = p0;
    float* deg = (float*)p;          p += (size_t)N * 4;
    unsigned* cnt = (unsigned*)p;    p += (size_t)N * 4;   // adjacent to deg: one memset
    float* dis = (float*)p;          p += (size_t)N * 4;
    p = (char*)(((uintptr_t)p + 255) & ~(uintptr_t)255);
    int2* ell = (int2*)p;            p += (size_t)N * MAXDEG * 8;
    p = (char*)(((uintptr_t)p + 255) & ~(uintptr_t)255);
    unsigned short* bufXW1 = (unsigned short*)p; p += (size_t)N * 768 * 2;  // layer-1 xw
    unsigned short* bufXW2 = (unsigned short*)p; p += (size_t)N * 768 * 2;  // layer-2 xw

    const size_t need = (size_t)(p - p0);
    if (ws_size < need) {
        hipMemsetAsync(d_out, 0, (size_t)out_size * 4, stream);   // sentinel
        return;
    }

    hipMemsetAsync(deg, 0, (size_t)N * 8, stream);

    const int eb  = (E + 255) / 256;
    const int nb8 = (N + 7) / 8;
    const int nb4 = (N + 3) / 4;
    k_build_ell<<<eb, 256, 0, stream>>>(ei, ew, deg, cnt, ell, E);
    k_dis<<<(N + 255) / 256, 256, 0, stream>>>(deg, dis, N);
    k_norm<<<(N * MAXDEG + 255) / 256, 256, 0, stream>>>(ell, cnt, dis, N);

    // layer 1 (conv+IN+ReLU+gemm, MFMA) -> bufXW1
    k_layer_a<32><<<nb8, 512, 0, stream>>>(x, cw1, gm1, bt1, gw1, bufXW1, N);
    // fused: layer-1 aggregation + layer-2 conv/IN/ReLU/gemm -> bufXW2
    k_gather_a<<<nb8, 512, 0, stream>>>(bufXW1, ell, cnt, dis, gb1,
                                        cw2, gm2, bt2, gw2, bufXW2, N);
    // final: layer-2 aggregation + mean_t + head -> d_out
    k_final<<<nb4, 256, 0, stream>>>(bufXW2, ell, cnt, dis, gb2, ow, ob, (float*)d_out, N);
}

// Round 13
// 193.979 us; speedup vs baseline: 1.9853x; 1.1059x over previous
//
#include <hip/hip_runtime.h>
#include <hip/hip_bf16.h>
#include <stdint.h>

#define MAXDEG 64

typedef short s16x8 __attribute__((ext_vector_type(8)));
typedef short s16x4 __attribute__((ext_vector_type(4)));
typedef float f32x4 __attribute__((ext_vector_type(4)));

static __device__ __forceinline__ float us2f(unsigned short u) {
    union { float f; unsigned int i; } cv; cv.i = ((unsigned int)u) << 16; return cv.f;
}
static __device__ __forceinline__ unsigned short f2us(float f) {
    __hip_bfloat16 h = __float2bfloat16(f);   // RNE
    return *(unsigned short*)&h;
}

// ---------------- setup: degree + ELL adjacency (incoming edges per dst) ----------------
__global__ void k_build_ell(const int* __restrict__ ei, const float* __restrict__ ew,
                            float* __restrict__ deg, unsigned* __restrict__ cnt,
                            int2* __restrict__ ell, int E)
{
    int e = blockIdx.x * 256 + threadIdx.x;
    if (e >= E) return;
    int s = ei[e], d = ei[E + e];
    float w = ew[e];
    atomicAdd(&deg[d], w);
    unsigned slot = atomicAdd(&cnt[d], 1u);
    if (slot < MAXDEG) ell[(size_t)d * MAXDEG + slot] = make_int2(s, __float_as_int(w));
}

// ---- precompute edge norm rsqrt(deg_s+1)*w*rsqrt(deg_d+1) into ELL payload ----
__global__ void k_norm(int2* __restrict__ ell, const unsigned* __restrict__ cnt,
                       const float* __restrict__ deg, int N)
{
    int idx = blockIdx.x * 256 + threadIdx.x;
    if (idx >= N * MAXDEG) return;
    int n = idx >> 6;               // MAXDEG = 64
    int s = idx & (MAXDEG - 1);
    unsigned dg = cnt[n]; if (dg > MAXDEG) dg = MAXDEG;
    if ((unsigned)s >= dg) return;
    int2 p = ell[idx];
    unsigned sx = (unsigned)p.x;
    float nrm = (sx < (unsigned)N)
        ? rsqrtf(deg[sx] + 1.0f) * __int_as_float(p.y) * rsqrtf(deg[n] + 1.0f) : 0.f;
    ell[idx] = make_int2(p.x, __float_as_int(nrm));
}

// lane-L edge gather: 3 x ushort4 from a 1536B bf16 row + 12 fma
#define ACCE(NRM, V0, V1, V2)                                                          \
    a[0] = fmaf(NRM, us2f(V0.x), a[0]);  a[1] = fmaf(NRM, us2f(V0.y), a[1]);           \
    a[2] = fmaf(NRM, us2f(V0.z), a[2]);  a[3] = fmaf(NRM, us2f(V0.w), a[3]);           \
    a[4] = fmaf(NRM, us2f(V1.x), a[4]);  a[5] = fmaf(NRM, us2f(V1.y), a[5]);           \
    a[6] = fmaf(NRM, us2f(V1.z), a[6]);  a[7] = fmaf(NRM, us2f(V1.w), a[7]);           \
    a[8] = fmaf(NRM, us2f(V2.x), a[8]);  a[9] = fmaf(NRM, us2f(V2.y), a[9]);           \
    a[10] = fmaf(NRM, us2f(V2.z), a[10]); a[11] = fmaf(NRM, us2f(V2.w), a[11]);

#define EDGE_GATHER(P)                                                      \
    {                                                                       \
        unsigned sx = (unsigned)(P).x;                                      \
        if (sx >= (unsigned)N) sx = 0;        /* nrm already 0 (k_norm) */  \
        float nrm = __int_as_float((P).y);                                  \
        const unsigned short* qp = xw_in + (size_t)sx * 768 + L * 4;        \
        ushort4 w0 = *(const ushort4*)qp;                                   \
        ushort4 w1 = *(const ushort4*)(qp + 256);                           \
        ushort4 w2 = *(const ushort4*)(qp + 512);                           \
        ACCE(nrm, w0, w1, w2)                                               \
    }

// ---------------- layer A (MFMA, conv-as-3-shifted-GEMMs), layer-1 only ---------------
template<int CIN>
__global__ __launch_bounds__(512, 4) void k_layer_a(
    const float* __restrict__ x_in,   // [T][N][CIN] f32
    const float* __restrict__ cw,     // [64][CIN][3] f32
    const float* __restrict__ gm, const float* __restrict__ bt,
    const float* __restrict__ gw,     // [64][64] f32
    unsigned short* __restrict__ xw_out, int N)
{
    constexpr int KT   = CIN / 32;
    constexpr int WSTR = (CIN == 64) ? 72 : 40;
    __shared__ __align__(16) short WT[3 * 64 * WSTR];  // WT[kk][c][ci]
    __shared__ __align__(16) short gwT[64 * 72];       // gwT[d][cc]
    __shared__ __align__(16) short xh[8][14 * 72];

    const int tid = threadIdx.x;
    const int nn = tid >> 6;
    const int c = tid & 63;
    const int m = c & 15;
    const int q = c >> 4;
    const int mrow = (m < 12) ? m : 11;
    int n = blockIdx.x * 8 + nn;
    if (n >= N) n = N - 1;

    for (int g = tid; g < 3 * 64 * CIN; g += 512) {
        int kk = g / (64 * CIN);
        int r = g - kk * 64 * CIN;
        int cc = r / CIN, ci = r - cc * CIN;
        WT[kk * (64 * WSTR) + cc * WSTR + ci] = (short)f2us(cw[(cc * CIN + ci) * 3 + kk]);
    }
    for (int g = tid; g < 4096; g += 512) {
        int cc = g >> 6, d = g & 63;
        gwT[d * 72 + cc] = (short)f2us(gw[g]);
    }
    #pragma unroll
    for (int it = 0; it < (12 * CIN) / 64; ++it) {
        int i = it * 64 + c;
        int t = i / CIN, ci = i - t * CIN;
        xh[nn][(t + 1) * 72 + ci] = (short)f2us(x_in[((size_t)t * N + n) * CIN + ci]);
    }
    if (c < CIN) { xh[nn][c] = 0; xh[nn][13 * 72 + c] = 0; }
    __syncthreads();

    f32x4 acc[4];
    #pragma unroll
    for (int nt = 0; nt < 4; ++nt) acc[nt] = (f32x4){0.f, 0.f, 0.f, 0.f};
    #pragma unroll
    for (int kk = 0; kk < 3; ++kk) {
        #pragma unroll
        for (int kt = 0; kt < KT; ++kt) {
            s16x8 aA = *(const s16x8*)&xh[nn][(mrow + kk) * 72 + kt * 32 + q * 8];
            #pragma unroll
            for (int nt = 0; nt < 4; ++nt) {
                s16x8 bB = *(const s16x8*)&WT[kk * (64 * WSTR) + (nt * 16 + m) * WSTR + kt * 32 + q * 8];
                acc[nt] = __builtin_amdgcn_mfma_f32_16x16x32_bf16(aA, bB, acc[nt], 0, 0, 0);
            }
        }
    }

    #pragma unroll
    for (int nt = 0; nt < 4; ++nt) {
        float s  = acc[nt][0] + acc[nt][1] + acc[nt][2] + acc[nt][3];
        float s2 = acc[nt][0] * acc[nt][0] + acc[nt][1] * acc[nt][1]
                 + acc[nt][2] * acc[nt][2] + acc[nt][3] * acc[nt][3];
        if (q == 3) { s = 0.f; s2 = 0.f; }
        s  += __shfl_xor(s, 16);  s  += __shfl_xor(s, 32);
        s2 += __shfl_xor(s2, 16); s2 += __shfl_xor(s2, 32);
        const float mu  = s * (1.f / 12.f);
        const float var = s2 * (1.f / 12.f) - mu * mu;
        const float scn = rsqrtf(var + 1e-5f) * gm[nt * 16 + m];
        const float sbn = bt[nt * 16 + m];
        if (q < 3) {
            #pragma unroll
            for (int reg = 0; reg < 4; ++reg) {
                float h = fmaf(acc[nt][reg] - mu, scn, sbn);
                h = h > 0.f ? h : 0.f;
                xh[nn][(q * 4 + reg) * 72 + nt * 16 + m] = (short)f2us(h);
            }
        }
    }

    s16x8 a2[2];
    #pragma unroll
    for (int kt2 = 0; kt2 < 2; ++kt2)
        a2[kt2] = *(const s16x8*)&xh[nn][mrow * 72 + kt2 * 32 + q * 8];
    f32x4 acc2[4];
    #pragma unroll
    for (int nt = 0; nt < 4; ++nt) acc2[nt] = (f32x4){0.f, 0.f, 0.f, 0.f};
    #pragma unroll
    for (int nt = 0; nt < 4; ++nt) {
        #pragma unroll
        for (int kt2 = 0; kt2 < 2; ++kt2) {
            s16x8 b2 = *(const s16x8*)&gwT[(nt * 16 + m) * 72 + kt2 * 32 + q * 8];
            acc2[nt] = __builtin_amdgcn_mfma_f32_16x16x32_bf16(a2[kt2], b2, acc2[nt], 0, 0, 0);
        }
    }

    unsigned short* dst = xw_out + (size_t)n * 768;
    if (q < 3) {
        #pragma unroll
        for (int nt = 0; nt < 4; ++nt)
            #pragma unroll
            for (int reg = 0; reg < 4; ++reg)
                dst[(q * 4 + reg) * 64 + nt * 16 + m] = f2us(acc2[nt][reg]);
    }
}

// ---------------- fused: layer-1 aggregation + layer-2 conv/IN/ReLU/gemm ---------------
// Emits ONLY rowmean[n][64] = (1/12) * sum_t xw2[n][t][:]  (the final aggregation + head
// commute with mean_t, so the full [T][64] xw2 is never materialized).
__global__ __launch_bounds__(512, 4) void k_gather_a(
    const unsigned short* __restrict__ xw_in,   // [N][768] bf16 (layer-1 xw)
    const int2* __restrict__ ell, const unsigned* __restrict__ cnt,
    const float* __restrict__ deg, const float* __restrict__ gb,   // gb1
    const float* __restrict__ cw,   // cw2 [64][64][3]
    const float* __restrict__ gm, const float* __restrict__ bt,    // gm2, bt2
    const float* __restrict__ gw,   // gw2 [64][64]
    unsigned short* __restrict__ rowmean, int N)
{
    constexpr int WSTR = 72;
    __shared__ __align__(16) short WT[3 * 64 * WSTR];
    __shared__ __align__(16) short gwT[64 * 72];
    __shared__ __align__(16) short xh[8][14 * 72];

    const int tid = threadIdx.x;
    const int nn = tid >> 6;
    const int L = tid & 63;
    const int m = L & 15;
    const int q = L >> 4;
    const int mrow = (m < 12) ? m : 11;
    int n = blockIdx.x * 8 + nn;
    if (n >= N) n = N - 1;

    // stage layer-2 weights
    for (int g = tid; g < 3 * 64 * 64; g += 512) {
        int kk = g >> 12;
        int r = g & 4095;
        int cc = r >> 6, ci = r & 63;
        WT[kk * (64 * WSTR) + cc * WSTR + ci] = (short)f2us(cw[(cc * 64 + ci) * 3 + kk]);
    }
    for (int g = tid; g < 4096; g += 512) {
        int cc = g >> 6, d = g & 63;
        gwT[d * 72 + cc] = (short)f2us(gw[g]);
    }
    xh[nn][L] = 0; xh[nn][13 * 72 + L] = 0;    // conv zero-pad rows
    __syncthreads();

    // ---- gather: agg[t][c] for this node, in registers ----
    const float dn = rsqrtf(deg[n] + 1.0f);
    const float d2 = dn * dn;
    float a[12];
    {
        const unsigned short* self = xw_in + (size_t)n * 768 + L * 4;
        ushort4 v0 = *(const ushort4*)self;
        ushort4 v1 = *(const ushort4*)(self + 256);
        ushort4 v2 = *(const ushort4*)(self + 512);
        const int c0 = (L * 4) & 63;
        const float g0 = gb[c0], g1 = gb[c0 + 1], g2 = gb[c0 + 2], g3 = gb[c0 + 3];
        a[0] = fmaf(d2, us2f(v0.x), g0); a[1] = fmaf(d2, us2f(v0.y), g1);
        a[2] = fmaf(d2, us2f(v0.z), g2); a[3] = fmaf(d2, us2f(v0.w), g3);
        a[4] = fmaf(d2, us2f(v1.x), g0); a[5] = fmaf(d2, us2f(v1.y), g1);
        a[6] = fmaf(d2, us2f(v1.z), g2); a[7] = fmaf(d2, us2f(v1.w), g3);
        a[8] = fmaf(d2, us2f(v2.x), g0); a[9] = fmaf(d2, us2f(v2.y), g1);
        a[10] = fmaf(d2, us2f(v2.z), g2); a[11] = fmaf(d2, us2f(v2.w), g3);
    }
    unsigned dg = cnt[n]; if (dg > MAXDEG) dg = MAXDEG;
    const int2* row = ell + (size_t)n * MAXDEG;
    unsigned e = 0;
    for (; e + 4 <= dg; e += 4) {
        int2 p0 = row[e], p1 = row[e + 1], p2 = row[e + 2], p3 = row[e + 3];
        EDGE_GATHER(p0) EDGE_GATHER(p1) EDGE_GATHER(p2) EDGE_GATHER(p3)
    }
    for (; e < dg; ++e) { int2 p0 = row[e]; EDGE_GATHER(p0) }

    // ---- pack agg (bf16) into xh rows 1..12: lane L comp m -> t = j*4+q, ci = (4L+m)&63
    #pragma unroll
    for (int j = 0; j < 3; ++j) {
        s16x4 s4 = { (short)f2us(a[j * 4 + 0]), (short)f2us(a[j * 4 + 1]),
                     (short)f2us(a[j * 4 + 2]), (short)f2us(a[j * 4 + 3]) };
        *(s16x4*)&xh[nn][(j * 4 + q + 1) * 72 + ((L * 4) & 63)] = s4;
    }

    // ---- layer-2 conv (3 shifted GEMMs) ----
    f32x4 acc[4];
    #pragma unroll
    for (int nt = 0; nt < 4; ++nt) acc[nt] = (f32x4){0.f, 0.f, 0.f, 0.f};
    #pragma unroll
    for (int kk = 0; kk < 3; ++kk) {
        #pragma unroll
        for (int kt = 0; kt < 2; ++kt) {
            s16x8 aA = *(const s16x8*)&xh[nn][(mrow + kk) * 72 + kt * 32 + q * 8];
            #pragma unroll
            for (int nt = 0; nt < 4; ++nt) {
                s16x8 bB = *(const s16x8*)&WT[kk * (64 * WSTR) + (nt * 16 + m) * WSTR + kt * 32 + q * 8];
                acc[nt] = __builtin_amdgcn_mfma_f32_16x16x32_bf16(aA, bB, acc[nt], 0, 0, 0);
            }
        }
    }

    // ---- InstanceNorm + ReLU -> xh rows 0..11 ----
    #pragma unroll
    for (int nt = 0; nt < 4; ++nt) {
        float s  = acc[nt][0] + acc[nt][1] + acc[nt][2] + acc[nt][3];
        float s2 = acc[nt][0] * acc[nt][0] + acc[nt][1] * acc[nt][1]
                 + acc[nt][2] * acc[nt][2] + acc[nt][3] * acc[nt][3];
        if (q == 3) { s = 0.f; s2 = 0.f; }
        s  += __shfl_xor(s, 16);  s  += __shfl_xor(s, 32);
        s2 += __shfl_xor(s2, 16); s2 += __shfl_xor(s2, 32);
        const float mu  = s * (1.f / 12.f);
        const float var = s2 * (1.f / 12.f) - mu * mu;
        const float scn = rsqrtf(var + 1e-5f) * gm[nt * 16 + m];
        const float sbn = bt[nt * 16 + m];
        if (q < 3) {
            #pragma unroll
            for (int reg = 0; reg < 4; ++reg) {
                float h = fmaf(acc[nt][reg] - mu, scn, sbn);
                h = h > 0.f ? h : 0.f;
                xh[nn][(q * 4 + reg) * 72 + nt * 16 + m] = (short)f2us(h);
            }
        }
    }

    // ---- gemm2: xw2 = h @ gw2 ----
    s16x8 a2[2];
    #pragma unroll
    for (int kt2 = 0; kt2 < 2; ++kt2)
        a2[kt2] = *(const s16x8*)&xh[nn][mrow * 72 + kt2 * 32 + q * 8];
    f32x4 acc2[4];
    #pragma unroll
    for (int nt = 0; nt < 4; ++nt) acc2[nt] = (f32x4){0.f, 0.f, 0.f, 0.f};
    #pragma unroll
    for (int nt = 0; nt < 4; ++nt) {
        #pragma unroll
        for (int kt2 = 0; kt2 < 2; ++kt2) {
            s16x8 b2 = *(const s16x8*)&gwT[(nt * 16 + m) * 72 + kt2 * 32 + q * 8];
            acc2[nt] = __builtin_amdgcn_mfma_f32_16x16x32_bf16(a2[kt2], b2, acc2[nt], 0, 0, 0);
        }
    }

    // ---- rowmean[n][d] = (1/12) * sum_{t<12} xw2[t][d]  (rows 12..15 excluded) ----
    #pragma unroll
    for (int nt = 0; nt < 4; ++nt) {
        float pm = (q < 3) ? (acc2[nt][0] + acc2[nt][1] + acc2[nt][2] + acc2[nt][3]) : 0.f;
        pm += __shfl_xor(pm, 16); pm += __shfl_xor(pm, 32);
        if (q == 0)
            rowmean[(size_t)n * 64 + nt * 16 + m] = f2us(pm * (1.f / 12.f));
    }
}

// ---------------- final: rowmean aggregation + 64x32 head ------------------------------
// out[n] = ( d2*rowmean[n] + gb + sum_e nrm*rowmean[src] ) @ ow + ob
__global__ __launch_bounds__(256) void k_final(
    const unsigned short* __restrict__ rowmean, const int2* __restrict__ ell,
    const unsigned* __restrict__ cnt, const float* __restrict__ deg,
    const float* __restrict__ gb,
    const float* __restrict__ ow, const float* __restrict__ ob,
    float* __restrict__ dout, int N)
{
    __shared__ __align__(16) float hbuf[4][64];
    const int tid = threadIdx.x;
    const int nn = tid >> 6, L = tid & 63;
    int n = blockIdx.x * 4 + nn;
    if (n >= N) n = N - 1;
    const float dn = rsqrtf(deg[n] + 1.0f);
    const float d2 = dn * dn;

    float a = fmaf(d2, us2f(rowmean[(size_t)n * 64 + L]), gb[L]);

    unsigned dg = cnt[n]; if (dg > MAXDEG) dg = MAXDEG;
    const int2* row = ell + (size_t)n * MAXDEG;
    unsigned e = 0;
    for (; e + 8 <= dg; e += 8) {
        #pragma unroll
        for (int i = 0; i < 8; ++i) {
            int2 p = row[e + i];
            unsigned sx = (unsigned)p.x;
            if (sx >= (unsigned)N) sx = 0;            // nrm already 0
            a = fmaf(__int_as_float(p.y), us2f(rowmean[(size_t)sx * 64 + L]), a);
        }
    }
    for (; e < dg; ++e) {
        int2 p = row[e];
        unsigned sx = (unsigned)p.x;
        if (sx >= (unsigned)N) sx = 0;
        a = fmaf(__int_as_float(p.y), us2f(rowmean[(size_t)sx * 64 + L]), a);
    }

    hbuf[nn][L] = a;
    __syncthreads();
    if (L < 32) {
        float oa = ob[L];
        #pragma unroll
        for (int cc = 0; cc < 64; ++cc)
            oa = fmaf(hbuf[nn][cc], ow[cc * 32 + L], oa);
        dout[(size_t)n * 32 + L] = oa;
    }
}

extern "C" void kernel_launch(void* const* d_in, const int* in_sizes, int n_in,
                              void* d_out, int out_size, void* d_ws, size_t ws_size,
                              hipStream_t stream)
{
    const float* x   = (const float*)d_in[0];
    const int*   ei  = (const int*)d_in[1];
    const float* ew  = (const float*)d_in[2];
    const float* cw1 = (const float*)d_in[3];
    const float* gm1 = (const float*)d_in[5];
    const float* bt1 = (const float*)d_in[6];
    const float* gw1 = (const float*)d_in[7];
    const float* gb1 = (const float*)d_in[8];
    const float* cw2 = (const float*)d_in[9];
    const float* gm2 = (const float*)d_in[11];
    const float* bt2 = (const float*)d_in[12];
    const float* gw2 = (const float*)d_in[13];
    const float* gb2 = (const float*)d_in[14];
    const float* ow  = (const float*)d_in[15];
    const float* ob  = (const float*)d_in[16];

    const int N = in_sizes[0] / (12 * 32);
    const int E = in_sizes[2];

    // workspace layout
    char* p0 = (char*)d_ws;
    char* p = p0;
    float* deg = (float*)p;          p += (size_t)N * 4;
    unsigned* cnt = (unsigned*)p;    p += (size_t)N * 4;   // adjacent to deg: one memset
    p = (char*)(((uintptr_t)p + 255) & ~(uintptr_t)255);
    int2* ell = (int2*)p;            p += (size_t)N * MAXDEG * 8;
    p = (char*)(((uintptr_t)p + 255) & ~(uintptr_t)255);
    unsigned short* bufXW1 = (unsigned short*)p; p += (size_t)N * 768 * 2;  // layer-1 xw
    unsigned short* rowmean = (unsigned short*)p; p += (size_t)N * 64 * 2;  // mean_t xw2

    const size_t need = (size_t)(p - p0);
    if (ws_size < need) {
        hipMemsetAsync(d_out, 0, (size_t)out_size * 4, stream);   // sentinel
        return;
    }

    hipMemsetAsync(deg, 0, (size_t)N * 8, stream);

    const int eb  = (E + 255) / 256;
    const int nb8 = (N + 7) / 8;
    const int nb4 = (N + 3) / 4;
    k_build_ell<<<eb, 256, 0, stream>>>(ei, ew, deg, cnt, ell, E);
    k_norm<<<(N * MAXDEG + 255) / 256, 256, 0, stream>>>(ell, cnt, deg, N);

    // layer 1 (conv+IN+ReLU+gemm, MFMA) -> bufXW1
    k_layer_a<32><<<nb8, 512, 0, stream>>>(x, cw1, gm1, bt1, gw1, bufXW1, N);
    // fused: layer-1 aggregation + layer-2 conv/IN/ReLU/gemm -> rowmean (mean_t of xw2)
    k_gather_a<<<nb8, 512, 0, stream>>>(bufXW1, ell, cnt, deg, gb1,
                                        cw2, gm2, bt2, gw2, rowmean, N);
    // final: rowmean aggregation + head -> d_out
    k_final<<<nb4, 256, 0, stream>>>(rowmean, ell, cnt, deg, gb2, ow, ob, (float*)d_out, N);
}